// Round 11
// baseline (1306.728 us; speedup 1.0000x reference)
//
#include <hip/hip_runtime.h>
#include <hip/hip_bf16.h>

#define N_MOLS      64
#define N_CONFS_PER 10
#define A_ATOMS     40
#define N_CONFS     640
#define N_ATOMS     25600
#define N_EDGES     409600
#define D           256
#define NG          32
#define NLAYERS     4
#define MOLB        512
#define H_MOL       384
#define EDGE_CAP    1024
#define EB          64    // edge batch
#define NBMAX       16    // max batches
#define SHBP        36    // sHb row stride (halfwords)
#define SEFP        260   // sEFs row stride (halfwords)
#define SRP         260   // f32 residual row stride (dwords)
#define SBH         256   // bf16 tile row stride (halfwords), XOR-swizzled
#define TPB         512   // 8 waves

typedef __attribute__((ext_vector_type(8))) short bshort8;
typedef __attribute__((ext_vector_type(4))) float f32x4;

// swizzled halfword index into a [48][SBH] bf16 tile: conflict-free b128 A-frag reads
#define SWZ(row, hw) (((row) << 8) + ((hw) ^ (((row) & 7) << 3)))

__device__ __forceinline__ float sspf(float x) {
    return fmaxf(x, 0.f) + log1pf(expf(-fabsf(x))) - 0.69314718055994531f;
}
__device__ __forceinline__ float b2f(short s) {
    union { unsigned u; float f; } u;
    u.u = ((unsigned)(unsigned short)s) << 16;
    return u.f;
}
// fast bf16 (round-half-up == RNE except exact ties): 2 inst
__device__ __forceinline__ short f2bf(float x) {
    return (short)(unsigned short)((__float_as_uint(x) + 0x8000u) >> 16);
}
// pack two floats -> u32 of 2 bf16 (lo_e in low hw): 2 adds + 1 v_perm
__device__ __forceinline__ unsigned pkbf(float lo_e, float hi_e) {
    return __builtin_amdgcn_perm(__float_as_uint(hi_e) + 0x8000u,
                                 __float_as_uint(lo_e) + 0x8000u, 0x07060302u);
}

// ---------------- weight prep: dense W[l][k][n] fp32 -> WT[mat][l][n][k] bf16 ----------------
__global__ __launch_bounds__(256) void k_prep(const float* __restrict__ Wn,
                                              const float* __restrict__ Wu1,
                                              const float* __restrict__ Wu2,
                                              __hip_bfloat16* __restrict__ WT) {
    int idx = blockIdx.x * 256 + threadIdx.x;       // 3*4*256*256
    int k = idx & 255;
    int n = (idx >> 8) & 255;
    int l = (idx >> 16) & 3;
    int mat = idx >> 18;
    const float* src = (mat == 0) ? Wn : (mat == 1) ? Wu1 : Wu2;
    WT[idx] = __float2bfloat16(src[((size_t)l * 256 + k) * 256 + n]);
}

// WT2[l][n][k] bf16 from We2[l][k][n]; We1T[l][t][m] bf16 from We1[l][m][t]
__global__ __launch_bounds__(256) void k_prep2(const float* __restrict__ We2,
                                               const float* __restrict__ We1,
                                               __hip_bfloat16* __restrict__ WT2,
                                               __hip_bfloat16* __restrict__ We1T) {
    int idx = blockIdx.x * 256 + threadIdx.x;       // 32768 + 4096
    if (idx < 32768) {
        int k = idx & 31;
        int n = (idx >> 5) & 255;
        int l = idx >> 13;
        WT2[idx] = __float2bfloat16(We2[((size_t)l * 32 + k) * 256 + n]);
    } else {
        int j = idx - 32768;
        int m = j & 31;
        int t = (j >> 5) & 31;
        int l = j >> 10;
        We1T[j] = __float2bfloat16(We1[((size_t)l * 32 + m) * 32 + t]);
    }
}

// ---------------- edge bucketing by conformer ----------------
__global__ __launch_bounds__(256) void k_scatter(const int* __restrict__ nbr,
                                                 unsigned* __restrict__ cursors,
                                                 unsigned* __restrict__ esort) {
    int e = blockIdx.x * 256 + threadIdx.x;
    if (e >= N_EDGES) return;
    int a0 = nbr[2 * e], a1 = nbr[2 * e + 1];
    int conf = a0 / A_ATOMS;
    int a0l = a0 - conf * A_ATOMS;
    int a1l = a1 - conf * A_ATOMS;
    unsigned r = atomicAdd(&cursors[conf], 1u);
    if (r < EDGE_CAP) esort[conf * EDGE_CAP + r] = (unsigned)((a0l << 6) | a1l);
}

// dense MFMA from bf16 swizzled tile: wave -> 3 m-tiles x n-tiles {2wv, 2wv+1}
__device__ __forceinline__ void mfma_dense8b(const short* __restrict__ src,
                                             const __hip_bfloat16* __restrict__ WT,
                                             f32x4 acc[3][2], int lane, int wv) {
    const int r = lane & 15, g = lane >> 4;
#pragma unroll
    for (int mt = 0; mt < 3; ++mt)
#pragma unroll
        for (int j = 0; j < 2; ++j) acc[mt][j] = (f32x4){0.f, 0.f, 0.f, 0.f};
#pragma unroll 2
    for (int kt = 0; kt < 8; ++kt) {
        const int ko = kt * 32 + g * 8;
        bshort8 a0 = *(const bshort8*)&src[SWZ(0 * 16 + r, ko)];
        bshort8 a1 = *(const bshort8*)&src[SWZ(1 * 16 + r, ko)];
        bshort8 a2 = *(const bshort8*)&src[SWZ(2 * 16 + r, ko)];
#pragma unroll
        for (int j = 0; j < 2; ++j) {
            const int nt = wv * 2 + j;
            bshort8 b = *(const bshort8*)&WT[(nt * 16 + r) * 256 + ko];
            acc[0][j] = __builtin_amdgcn_mfma_f32_16x16x32_bf16(a0, b, acc[0][j], 0, 0, 0);
            acc[1][j] = __builtin_amdgcn_mfma_f32_16x16x32_bf16(a1, b, acc[1][j], 0, 0, 0);
            acc[2][j] = __builtin_amdgcn_mfma_f32_16x16x32_bf16(a2, b, acc[2][j], 0, 0, 0);
        }
    }
}

// writeback: MODE 0: dst16 = bf16(acc+bias) ; 1: dst16 = bf16(ssp(acc+bias)) ;
//            2: dstR += acc+bias (f32) and dst16 = bf16(new r)
template <int MODE>
__device__ __forceinline__ void mfma_wb8b(const f32x4 acc[3][2], short* __restrict__ dst16,
                                          float* __restrict__ dstR,
                                          const float* __restrict__ bias, int lane, int wv) {
    const int cc = lane & 15, g = lane >> 4;
    const int cr = g * 4;
#pragma unroll
    for (int j = 0; j < 2; ++j) {
        const int col = (wv * 2 + j) * 16 + cc;
        const float bv = bias[col];
#pragma unroll
        for (int mt = 0; mt < 3; ++mt) {
            if (mt == 2 && g >= 2) continue;   // rows 40..47 are padding
#pragma unroll
            for (int reg = 0; reg < 4; ++reg) {
                const int row = mt * 16 + cr + reg;
                float v = acc[mt][j][reg] + bv;
                if (MODE == 1) v = sspf(v);
                if (MODE == 2) { v += dstR[row * SRP + col]; dstR[row * SRP + col] = v; }
                dst16[SWZ(row, col)] = f2bf(v);
            }
        }
    }
}

// ---------------- main per-conformer kernel: 512 threads, 8 waves ----------------
__global__ __launch_bounds__(TPB, 2) void k_main(
    const int* __restrict__ z, const float* __restrict__ xyz,
    const float* __restrict__ emb,
    const float* __restrict__ be1, const float* __restrict__ be2,
    const float* __restrict__ bn,
    const float* __restrict__ bu1, const float* __restrict__ bu2,
    const __hip_bfloat16* __restrict__ WT,
    const __hip_bfloat16* __restrict__ WT2,
    const __hip_bfloat16* __restrict__ We1T,
    const unsigned* __restrict__ cursors, const unsigned* __restrict__ esort,
    float* __restrict__ conf_fp)
{
    __shared__ float sR[48 * SRP];            // residual r f32 (49.9KB)
    __shared__ short sRb[48 * SBH];           // r bf16 mirror, swizzled (24.6KB)
    __shared__ short sBb[48 * SBH];           // rn -> agg -> t bf16, swizzled (24.6KB)
    __shared__ short sEFs[EB * SEFP];         // ef batch bf16 (33.3KB)
    __shared__ short sHb[2][EB * SHBP];       // h double-buffer bf16 (9.2KB)
    __shared__ float sDall[1152];             // scaled distances + zero pad (4.6KB)
    __shared__ unsigned sEdge[EDGE_CAP];      // packed edges (4KB)
    __shared__ unsigned short sCsr[2 * EDGE_CAP];       // (src<<10)|edge (4KB)
    __shared__ unsigned short sWin[A_ATOMS * (NBMAX + 1)]; // per-(atom,batch) cursor
    __shared__ int sPtr[A_ATOMS + 1];
    __shared__ int sDeg[A_ATOMS];
    __shared__ float sXYZ[A_ATOMS][3];
    __shared__ int sZ[A_ATOMS];

    const int tid  = threadIdx.x;
    const int lane = tid & 63;
    const int wv   = tid >> 6;        // 0..7
    const int c4   = lane << 2;
    const int conf = blockIdx.x;
    const int fr = lane & 15, fg = lane >> 4, g8 = (lane >> 4) << 3;
    const int mtx = wv & 3;           // X2 m-tile
    const int ttx = wv >> 2;          // X2 t-tile

    if (tid < A_ATOMS) {
        int ga = conf * A_ATOMS + tid;
        sZ[tid] = z[ga];
        sXYZ[tid][0] = xyz[ga * 3 + 0];
        sXYZ[tid][1] = xyz[ga * 3 + 1];
        sXYZ[tid][2] = xyz[ga * 3 + 2];
        sDeg[tid] = 0;
    }
    for (int i = tid; i < 8 * SBH; i += TPB) {   // zero bf16 pad rows 40..47
        sRb[40 * SBH + i] = 0;
        sBb[40 * SBH + i] = 0;
    }
    __syncthreads();
    {   // embedding init: f32 + bf16 mirror
        const int c = tid & 255, q = tid >> 8;
        for (int aa = q; aa < A_ATOMS; aa += 2) {
            float v = emb[sZ[aa] * D + c];
            sR[aa * SRP + c] = v;
            sRb[SWZ(aa, c)] = f2bf(v);
        }
    }
    int cnt = (int)cursors[conf];
    if (cnt > EDGE_CAP) cnt = EDGE_CAP;
    const unsigned* eptr = esort + conf * EDGE_CAP;
    for (int i = tid; i < cnt; i += TPB) {
        unsigned pe = eptr[i];
        sEdge[i] = pe;
        int a0l = (pe >> 6) & 63, a1l = pe & 63;
        float dx = sXYZ[a0l][0] - sXYZ[a1l][0];
        float dy = sXYZ[a0l][1] - sXYZ[a1l][1];
        float dz = sXYZ[a0l][2] - sXYZ[a1l][2];
        sDall[i] = sqrtf(dx * dx + dy * dy + dz * dz) * (31.0f / 5.0f);
        atomicAdd(&sDeg[a0l], 1);
        atomicAdd(&sDeg[a1l], 1);
    }
    for (int i = cnt + tid; i < 1152; i += TPB) sDall[i] = 0.f;
    __syncthreads();
    if (tid == 0) {
        int s = 0;
        for (int a = 0; a < A_ATOMS; ++a) { sPtr[a] = s; s += sDeg[a]; }
        sPtr[A_ATOMS] = s;
    }
    __syncthreads();
    const int NB = (cnt + EB - 1) / EB;
    // ordered CSR fill + per-batch windows
    if (tid < A_ATOMS) {
        const int ps = sPtr[tid];
        int pos = ps;
        for (int i = 0; i < cnt; ++i) {
            unsigned pe = sEdge[i];
            int a0l = (pe >> 6) & 63, a1l = pe & 63;
            if (a0l == tid) sCsr[pos++] = (unsigned short)((a1l << 10) | i);
            if (a1l == tid) sCsr[pos++] = (unsigned short)((a0l << 10) | i);
        }
        int p = ps;
        for (int b = 0; b <= NB; ++b) {
            const int lim = b * EB;
            while (p < pos && (int)(sCsr[p] & 1023) < lim) ++p;
            sWin[tid * (NBMAX + 1) + b] = (unsigned short)p;
        }
    }

    for (int l = 0; l < NLAYERS; ++l) {
        __syncthreads();
        // ---- M1: sBb = bf16(r @ Wn + bn)
        {
            f32x4 acc[3][2];
            mfma_dense8b(sRb, WT + ((size_t)(0 * 4 + l) << 16), acc, lane, wv);
            mfma_wb8b<0>(acc, sBb, sR, bn + l * D, lane, wv);
        }
        __syncthreads();
        // ---- edge phase: balanced 2-barrier pipeline, batches of 64
        float4 agg[5];
#pragma unroll
        for (int k = 0; k < 5; ++k) agg[k] = make_float4(0.f, 0.f, 0.f, 0.f);
        {
            const bshort8 bf0 = *(const bshort8*)&WT2[(size_t)l * 8192 + ((2 * wv + 0) * 16 + fr) * 32 + g8];
            const bshort8 bf1 = *(const bshort8*)&WT2[(size_t)l * 8192 + ((2 * wv + 1) * 16 + fr) * 32 + g8];
            const float bb0 = be2[l * D + (2 * wv + 0) * 16 + fr];
            const float bb1 = be2[l * D + (2 * wv + 1) * 16 + fr];
            const bshort8 bfX = *(const bshort8*)&We1T[(size_t)l * 1024 + (ttx * 16 + fr) * 32 + g8];
            const float bbX = be1[l * NG + ttx * 16 + fr];

            // prologue: X2(0) -> sHb[0]
            if (NB > 0) {
                const float dd = sDall[mtx * 16 + fr];
                union { bshort8 v; unsigned u[4]; } ua;
#pragma unroll
                for (int j = 0; j < 4; ++j) {
                    const float u0 = dd - (float)(g8 + 2 * j + 0);
                    const float u1 = dd - (float)(g8 + 2 * j + 1);
                    ua.u[j] = pkbf(expf(-0.5f * u0 * u0), expf(-0.5f * u1 * u1));
                }
                f32x4 c = (f32x4){0.f, 0.f, 0.f, 0.f};
                c = __builtin_amdgcn_mfma_f32_16x16x32_bf16(ua.v, bfX, c, 0, 0, 0);
#pragma unroll
                for (int reg = 0; reg < 4; ++reg) {
                    const int erow = mtx * 16 + fg * 4 + reg;
                    sHb[0][erow * SHBP + ttx * 16 + fr] = f2bf(sspf(c[reg] + bbX));
                }
            }
            __syncthreads();
            for (int b = 0; b < NB; ++b) {
                const int base = b * EB;
                // ---- phase1: P4(b) then X2(b+1), every wave does both
                {
                    const short* __restrict__ hb = sHb[b & 1];
#pragma unroll
                    for (int mt = 0; mt < 4; ++mt) {
                        union { bshort8 v; short4 s[2]; } af;
                        af.s[0] = *(const short4*)&hb[(mt * 16 + fr) * SHBP + g8];
                        af.s[1] = *(const short4*)&hb[(mt * 16 + fr) * SHBP + g8 + 4];
                        f32x4 c0 = (f32x4){0.f, 0.f, 0.f, 0.f};
                        c0 = __builtin_amdgcn_mfma_f32_16x16x32_bf16(af.v, bf0, c0, 0, 0, 0);
                        f32x4 c1 = (f32x4){0.f, 0.f, 0.f, 0.f};
                        c1 = __builtin_amdgcn_mfma_f32_16x16x32_bf16(af.v, bf1, c1, 0, 0, 0);
#pragma unroll
                        for (int reg = 0; reg < 4; ++reg) {
                            const int erow = mt * 16 + fg * 4 + reg;
                            sEFs[erow * SEFP + (2 * wv + 0) * 16 + fr] = f2bf(c0[reg] + bb0);
                            sEFs[erow * SEFP + (2 * wv + 1) * 16 + fr] = f2bf(c1[reg] + bb1);
                        }
                    }
                }
                if (b + 1 < NB) {
                    short* __restrict__ hb = sHb[(b + 1) & 1];
                    const float dd = sDall[(b + 1) * EB + mtx * 16 + fr];
                    union { bshort8 v; unsigned u[4]; } ua;
#pragma unroll
                    for (int j = 0; j < 4; ++j) {
                        const float u0 = dd - (float)(g8 + 2 * j + 0);
                        const float u1 = dd - (float)(g8 + 2 * j + 1);
                        ua.u[j] = pkbf(expf(-0.5f * u0 * u0), expf(-0.5f * u1 * u1));
                    }
                    f32x4 c = (f32x4){0.f, 0.f, 0.f, 0.f};
                    c = __builtin_amdgcn_mfma_f32_16x16x32_bf16(ua.v, bfX, c, 0, 0, 0);
#pragma unroll
                    for (int reg = 0; reg < 4; ++reg) {
                        const int erow = mtx * 16 + fg * 4 + reg;
                        hb[erow * SHBP + ttx * 16 + fr] = f2bf(sspf(c[reg] + bbX));
                    }
                }
                __syncthreads();
                // ---- phase2: P5 counted gathers (wave owns rows 5wv..5wv+4)
#pragma unroll
                for (int k = 0; k < 5; ++k) {
                    const int row = wv * 5 + k;
                    const int st = (int)sWin[row * (NBMAX + 1) + b];
                    const int en = (int)sWin[row * (NBMAX + 1) + b + 1];
                    for (int i = st; i < en; ++i) {
                        const int ent = (int)sCsr[i];
                        const int e = ent & 1023, src = ent >> 10;
                        const short4 f4 = *(const short4*)&sEFs[(e - base) * SEFP + c4];
                        const short4 r4 = *(const short4*)&sBb[SWZ(src, c4)];
                        agg[k].x = fmaf(b2f(f4.x), b2f(r4.x), agg[k].x);
                        agg[k].y = fmaf(b2f(f4.y), b2f(r4.y), agg[k].y);
                        agg[k].z = fmaf(b2f(f4.z), b2f(r4.z), agg[k].z);
                        agg[k].w = fmaf(b2f(f4.w), b2f(r4.w), agg[k].w);
                    }
                }
                __syncthreads();
            }
        }
        // agg -> sBb (rn dead)
#pragma unroll
        for (int k = 0; k < 5; ++k) {
            uint2 p;
            p.x = pkbf(agg[k].x, agg[k].y);
            p.y = pkbf(agg[k].z, agg[k].w);
            *(uint2*)&sBb[SWZ(wv * 5 + k, c4)] = p;
        }
        __syncthreads();
        // ---- M2: sBb = bf16(ssp(agg @ Wu1 + bu1))  (in-place: sync between acc and wb)
        {
            f32x4 acc[3][2];
            mfma_dense8b(sBb, WT + ((size_t)(1 * 4 + l) << 16), acc, lane, wv);
            __syncthreads();
            mfma_wb8b<1>(acc, sBb, sR, bu1 + l * D, lane, wv);
        }
        __syncthreads();
        // ---- M3: sR += t @ Wu2 + bu2 (f32) and refresh bf16 mirror sRb
        {
            f32x4 acc[3][2];
            mfma_dense8b(sBb, WT + ((size_t)(2 * 4 + l) << 16), acc, lane, wv);
            mfma_wb8b<2>(acc, sRb, sR, bu2 + l * D, lane, wv);
        }
    }
    __syncthreads();
    if (tid < D) {
        float s = 0.f;
#pragma unroll
        for (int a = 0; a < A_ATOMS; ++a) s += sR[a * SRP + tid];
        conf_fp[conf * D + tid] = s;
    }
}

// ---------------- per-conformer molecular MLP + Boltzmann-weighted reduce ----------------
__global__ __launch_bounds__(512) void k_mol(
    const float* __restrict__ conf_fp,
    const float* __restrict__ Wm1, const float* __restrict__ bm1,
    const float* __restrict__ Wm2, const float* __restrict__ bm2,
    const float* __restrict__ boltz, float* __restrict__ mol_fp)
{
    __shared__ float cf[D];
    __shared__ float t[H_MOL];
    const int conf = blockIdx.x;
    const int tid = threadIdx.x;
    if (tid < D) cf[tid] = conf_fp[conf * D + tid];
    __syncthreads();
    if (tid < H_MOL) {
        float s = bm1[tid];
        for (int k = 0; k < D; k += 4) {
            const float4 v = *(const float4*)&cf[k];
            s = fmaf(v.x, Wm1[(k + 0) * H_MOL + tid], s);
            s = fmaf(v.y, Wm1[(k + 1) * H_MOL + tid], s);
            s = fmaf(v.z, Wm1[(k + 2) * H_MOL + tid], s);
            s = fmaf(v.w, Wm1[(k + 3) * H_MOL + tid], s);
        }
        t[tid] = sspf(s);
    }
    __syncthreads();
    {
        const int m = tid;
        float s = bm2[m];
        for (int h = 0; h < H_MOL; h += 4) {
            const float4 v = *(const float4*)&t[h];
            s = fmaf(v.x, Wm2[(h + 0) * MOLB + m], s);
            s = fmaf(v.y, Wm2[(h + 1) * MOLB + m], s);
            s = fmaf(v.z, Wm2[(h + 2) * MOLB + m], s);
            s = fmaf(v.w, Wm2[(h + 3) * MOLB + m], s);
        }
        atomicAdd(&mol_fp[(conf / N_CONFS_PER) * MOLB + m], s * boltz[conf]);
    }
}

// ---------------- final readout MLP + sigmoid ----------------
__global__ __launch_bounds__(256) void k_final(
    const float* __restrict__ mol_fp,
    const float* __restrict__ Wr1, const float* __restrict__ br1,
    const float* __restrict__ Wr2, const float* __restrict__ br2,
    float* __restrict__ out)
{
    __shared__ float mf[MOLB];
    __shared__ float t2[D];
    __shared__ float red[4];
    const int mol = blockIdx.x, tid = threadIdx.x;
    mf[tid]       = mol_fp[mol * MOLB + tid];
    mf[tid + 256] = mol_fp[mol * MOLB + tid + 256];
    __syncthreads();
    {
        float s = br1[tid];
        for (int k = 0; k < MOLB; k += 4) {
            const float4 v = *(const float4*)&mf[k];
            s = fmaf(v.x, Wr1[(k + 0) * D + tid], s);
            s = fmaf(v.y, Wr1[(k + 1) * D + tid], s);
            s = fmaf(v.z, Wr1[(k + 2) * D + tid], s);
            s = fmaf(v.w, Wr1[(k + 3) * D + tid], s);
        }
        t2[tid] = sspf(s);
    }
    __syncthreads();
    float p = t2[tid] * Wr2[tid];
#pragma unroll
    for (int o = 32; o > 0; o >>= 1) p += __shfl_down(p, o);
    if ((tid & 63) == 0) red[tid >> 6] = p;
    __syncthreads();
    if (tid == 0) {
        float logit = red[0] + red[1] + red[2] + red[3] + br2[0];
        out[mol] = 1.f / (1.f + expf(-logit));
    }
}

extern "C" void kernel_launch(void* const* d_in, const int* in_sizes, int n_in,
                              void* d_out, int out_size, void* d_ws, size_t ws_size,
                              hipStream_t stream)
{
    const int*   z     = (const int*)d_in[0];
    const float* xyz   = (const float*)d_in[1];
    const int*   nbr   = (const int*)d_in[2];
    const float* boltz = (const float*)d_in[3];
    const float* emb   = (const float*)d_in[4];
    const float* We1   = (const float*)d_in[5];
    const float* be1   = (const float*)d_in[6];
    const float* We2   = (const float*)d_in[7];
    const float* be2   = (const float*)d_in[8];
    const float* Wn    = (const float*)d_in[9];
    const float* bn    = (const float*)d_in[10];
    const float* Wu1   = (const float*)d_in[11];
    const float* bu1   = (const float*)d_in[12];
    const float* Wu2   = (const float*)d_in[13];
    const float* bu2   = (const float*)d_in[14];
    const float* Wm1   = (const float*)d_in[15];
    const float* bm1   = (const float*)d_in[16];
    const float* Wm2   = (const float*)d_in[17];
    const float* bm2   = (const float*)d_in[18];
    const float* Wr1   = (const float*)d_in[19];
    const float* br1   = (const float*)d_in[20];
    const float* Wr2   = (const float*)d_in[21];
    const float* br2   = (const float*)d_in[22];

    char* ws = (char*)d_ws;
    unsigned* cursors        = (unsigned*)ws;                   // 2560 B
    float*    mol_fp         = (float*)(ws + 2560);             // 131072 B -> 133632
    unsigned* esort          = (unsigned*)(ws + 133632);        // 2621440 B -> 2755072
    float*    conf_fp        = (float*)(ws + 2755072);          // 655360 B -> 3410432
    __hip_bfloat16* WT       = (__hip_bfloat16*)(ws + 3410432); // 1572864 B -> 4983296
    __hip_bfloat16* WT2      = (__hip_bfloat16*)(ws + 4983296); // 65536 B -> 5048832
    __hip_bfloat16* We1T     = (__hip_bfloat16*)(ws + 5048832); // 8192 B -> 5057024

    hipMemsetAsync(cursors, 0, 2560 + 131072, stream);          // cursors + mol_fp
    k_prep<<<3072, 256, 0, stream>>>(Wn, Wu1, Wu2, WT);
    k_prep2<<<144, 256, 0, stream>>>(We2, We1, WT2, We1T);
    k_scatter<<<(N_EDGES + 255) / 256, 256, 0, stream>>>(nbr, cursors, esort);
    k_main<<<N_CONFS, TPB, 0, stream>>>(z, xyz, emb, be1, be2, bn,
                                        bu1, bu2, WT, WT2, We1T, cursors, esort, conf_fp);
    k_mol<<<N_CONFS, 512, 0, stream>>>(conf_fp, Wm1, bm1, Wm2, bm2, boltz, mol_fp);
    k_final<<<N_MOLS, 256, 0, stream>>>(mol_fp, Wr1, br1, Wr2, br2, (float*)d_out);
}

// Round 12
// 1131.750 us; speedup vs baseline: 1.1546x; 1.1546x over previous
//
#include <hip/hip_runtime.h>
#include <hip/hip_bf16.h>

#define N_MOLS      64
#define N_CONFS_PER 10
#define A_ATOMS     40
#define N_CONFS     640
#define N_ATOMS     25600
#define N_EDGES     409600
#define D           256
#define NG          32
#define NLAYERS     4
#define MOLB        512
#define H_MOL       384
#define EDGE_CAP    1024
#define EB          32    // edge batch
#define NBMAX       32    // max batches (EDGE_CAP/EB)
#define SHBP        36    // sHb row stride (halfwords)
#define SEFP        260   // sEFs row stride (halfwords)
#define SBH         256   // bf16 tile row stride (halfwords), XOR-swizzled
#define TPB         512   // 8 waves

typedef __attribute__((ext_vector_type(8))) short bshort8;
typedef __attribute__((ext_vector_type(4))) float f32x4;

// swizzled halfword index into a [48][SBH] bf16 tile (conflict-free b128 A-frag reads)
#define SWZ(row, hw) (((row) << 8) + ((hw) ^ (((row) & 7) << 3)))

__device__ __forceinline__ float sspf(float x) {
    return fmaxf(x, 0.f) + log1pf(expf(-fabsf(x))) - 0.69314718055994531f;
}
__device__ __forceinline__ float b2f(short s) {
    union { unsigned u; float f; } u;
    u.u = ((unsigned)(unsigned short)s) << 16;
    return u.f;
}
__device__ __forceinline__ short f2bf(float x) {
    return (short)(unsigned short)((__float_as_uint(x) + 0x8000u) >> 16);
}
__device__ __forceinline__ unsigned pkbf(float lo_e, float hi_e) {
    return __builtin_amdgcn_perm(__float_as_uint(hi_e) + 0x8000u,
                                 __float_as_uint(lo_e) + 0x8000u, 0x07060302u);
}

// ---------------- weight prep: dense W[l][k][n] fp32 -> WT[mat][l][n][k] bf16 ----------------
__global__ __launch_bounds__(256) void k_prep(const float* __restrict__ Wn,
                                              const float* __restrict__ Wu1,
                                              const float* __restrict__ Wu2,
                                              __hip_bfloat16* __restrict__ WT) {
    int idx = blockIdx.x * 256 + threadIdx.x;       // 3*4*256*256
    int k = idx & 255;
    int n = (idx >> 8) & 255;
    int l = (idx >> 16) & 3;
    int mat = idx >> 18;
    const float* src = (mat == 0) ? Wn : (mat == 1) ? Wu1 : Wu2;
    WT[idx] = __float2bfloat16(src[((size_t)l * 256 + k) * 256 + n]);
}

// WT2[l][n][k] bf16 from We2[l][k][n]; We1T[l][t][m] bf16 from We1[l][m][t]
__global__ __launch_bounds__(256) void k_prep2(const float* __restrict__ We2,
                                               const float* __restrict__ We1,
                                               __hip_bfloat16* __restrict__ WT2,
                                               __hip_bfloat16* __restrict__ We1T) {
    int idx = blockIdx.x * 256 + threadIdx.x;       // 32768 + 4096
    if (idx < 32768) {
        int k = idx & 31;
        int n = (idx >> 5) & 255;
        int l = idx >> 13;
        WT2[idx] = __float2bfloat16(We2[((size_t)l * 32 + k) * 256 + n]);
    } else {
        int j = idx - 32768;
        int m = j & 31;
        int t = (j >> 5) & 31;
        int l = j >> 10;
        We1T[j] = __float2bfloat16(We1[((size_t)l * 32 + m) * 32 + t]);
    }
}

// ---------------- edge bucketing by conformer ----------------
__global__ __launch_bounds__(256) void k_scatter(const int* __restrict__ nbr,
                                                 unsigned* __restrict__ cursors,
                                                 unsigned* __restrict__ esort) {
    int e = blockIdx.x * 256 + threadIdx.x;
    if (e >= N_EDGES) return;
    int a0 = nbr[2 * e], a1 = nbr[2 * e + 1];
    int conf = a0 / A_ATOMS;
    int a0l = a0 - conf * A_ATOMS;
    int a1l = a1 - conf * A_ATOMS;
    unsigned r = atomicAdd(&cursors[conf], 1u);
    if (r < EDGE_CAP) esort[conf * EDGE_CAP + r] = (unsigned)((a0l << 6) | a1l);
}

// dense MFMA from bf16 swizzled tile: wave -> 3 m-tiles x n-tiles {2wv, 2wv+1}
__device__ __forceinline__ void mfma_dense8b(const short* __restrict__ src,
                                             const __hip_bfloat16* __restrict__ WT,
                                             f32x4 acc[3][2], int lane, int wv) {
    const int r = lane & 15, g = lane >> 4;
#pragma unroll
    for (int mt = 0; mt < 3; ++mt)
#pragma unroll
        for (int j = 0; j < 2; ++j) acc[mt][j] = (f32x4){0.f, 0.f, 0.f, 0.f};
#pragma unroll 2
    for (int kt = 0; kt < 8; ++kt) {
        const int ko = kt * 32 + g * 8;
        bshort8 a0 = *(const bshort8*)&src[SWZ(0 * 16 + r, ko)];
        bshort8 a1 = *(const bshort8*)&src[SWZ(1 * 16 + r, ko)];
        bshort8 a2 = *(const bshort8*)&src[SWZ(2 * 16 + r, ko)];
#pragma unroll
        for (int j = 0; j < 2; ++j) {
            const int nt = wv * 2 + j;
            bshort8 b = *(const bshort8*)&WT[(nt * 16 + r) * 256 + ko];
            acc[0][j] = __builtin_amdgcn_mfma_f32_16x16x32_bf16(a0, b, acc[0][j], 0, 0, 0);
            acc[1][j] = __builtin_amdgcn_mfma_f32_16x16x32_bf16(a1, b, acc[1][j], 0, 0, 0);
            acc[2][j] = __builtin_amdgcn_mfma_f32_16x16x32_bf16(a2, b, acc[2][j], 0, 0, 0);
        }
    }
}

// writeback: MODE 0: dst16 = bf16(acc+bias) ; 1: dst16 = bf16(ssp(acc+bias))
template <int MODE>
__device__ __forceinline__ void mfma_wb8b(const f32x4 acc[3][2], short* __restrict__ dst16,
                                          const float* __restrict__ bias, int lane, int wv) {
    const int cc = lane & 15, g = lane >> 4;
    const int cr = g * 4;
#pragma unroll
    for (int j = 0; j < 2; ++j) {
        const int col = (wv * 2 + j) * 16 + cc;
        const float bv = bias[col];
#pragma unroll
        for (int mt = 0; mt < 3; ++mt) {
            if (mt == 2 && g >= 2) continue;   // rows 40..47 are padding
#pragma unroll
            for (int reg = 0; reg < 4; ++reg) {
                const int row = mt * 16 + cr + reg;
                float v = acc[mt][j][reg] + bv;
                if (MODE == 1) v = sspf(v);
                dst16[SWZ(row, col)] = f2bf(v);
            }
        }
    }
}

// ---------------- main per-conformer kernel: 512 threads, 8 waves, 2 blocks/CU ----------------
__global__ __launch_bounds__(TPB, 4) void k_main(
    const int* __restrict__ z, const float* __restrict__ xyz,
    const float* __restrict__ emb,
    const float* __restrict__ be1, const float* __restrict__ be2,
    const float* __restrict__ bn,
    const float* __restrict__ bu1, const float* __restrict__ bu2,
    const __hip_bfloat16* __restrict__ WT,
    const __hip_bfloat16* __restrict__ WT2,
    const __hip_bfloat16* __restrict__ We1T,
    const unsigned* __restrict__ cursors, const unsigned* __restrict__ esort,
    float* __restrict__ conf_fp)
{
    __shared__ short sRb[48 * SBH];           // r bf16, swizzled (24.6KB)
    __shared__ short sBb[48 * SBH];           // rn -> agg -> t bf16, swizzled (24.6KB)
    __shared__ __align__(16) char uEFbuf[EB * SEFP * 2];  // 16.6KB: sEFs | setup{xyz,z,deg} | colsum
    __shared__ __align__(16) char sHbBuf[2 * EB * SHBP * 2]; // 4.6KB: sHb | setup sEdge
    __shared__ float sDall[EDGE_CAP];         // scaled distances, zero-padded (4KB)
    __shared__ unsigned short sCsr[2 * EDGE_CAP];          // (src<<10)|edge (4KB)
    __shared__ unsigned short sWin[A_ATOMS * (NBMAX + 1)]; // per-(atom,batch) cursor (2.6KB)
    __shared__ int sPtr[A_ATOMS + 1];

    short* sEFs = (short*)uEFbuf;
    float* colsum = (float*)uEFbuf;
    float (*sXYZ)[3] = (float(*)[3])uEFbuf;       // setup alias
    int* sZ   = (int*)(uEFbuf + 480);             // setup alias
    int* sDeg = (int*)(uEFbuf + 640);             // setup alias
    short (*sHb)[EB * SHBP] = (short(*)[EB * SHBP])sHbBuf;
    unsigned* sEdge = (unsigned*)sHbBuf;          // setup alias (4KB <= 4.6KB)

    const int tid  = threadIdx.x;
    const int lane = tid & 63;
    const int wv   = tid >> 6;        // 0..7
    const int c4   = lane << 2;
    const int conf = blockIdx.x;
    const int fr = lane & 15, fg = lane >> 4, g8 = (lane >> 4) << 3;
    const int mtx = wv & 1;           // X2 m-tile (waves 0..3)
    const int ttx = (wv >> 1) & 1;    // X2 t-tile

    if (tid < A_ATOMS) {
        int ga = conf * A_ATOMS + tid;
        sZ[tid] = z[ga];
        sXYZ[tid][0] = xyz[ga * 3 + 0];
        sXYZ[tid][1] = xyz[ga * 3 + 1];
        sXYZ[tid][2] = xyz[ga * 3 + 2];
        sDeg[tid] = 0;
    }
    for (int i = tid; i < 8 * SBH; i += TPB) {   // zero bf16 pad rows 40..47
        sRb[40 * SBH + i] = 0;
        sBb[40 * SBH + i] = 0;
    }
    __syncthreads();
    float embsum = 0.f;
    {   // embedding init: bf16 r + f32 emb partial (rows q::2, col c)
        const int c = tid & 255, q = tid >> 8;
        for (int aa = q; aa < A_ATOMS; aa += 2) {
            float v = emb[sZ[aa] * D + c];
            embsum += v;
            sRb[SWZ(aa, c)] = f2bf(v);
        }
    }
    int cnt = (int)cursors[conf];
    if (cnt > EDGE_CAP) cnt = EDGE_CAP;
    const unsigned* eptr = esort + conf * EDGE_CAP;
    for (int i = tid; i < cnt; i += TPB) {
        unsigned pe = eptr[i];
        sEdge[i] = pe;
        int a0l = (pe >> 6) & 63, a1l = pe & 63;
        float dx = sXYZ[a0l][0] - sXYZ[a1l][0];
        float dy = sXYZ[a0l][1] - sXYZ[a1l][1];
        float dz = sXYZ[a0l][2] - sXYZ[a1l][2];
        sDall[i] = sqrtf(dx * dx + dy * dy + dz * dz) * (31.0f / 5.0f);
        atomicAdd(&sDeg[a0l], 1);
        atomicAdd(&sDeg[a1l], 1);
    }
    for (int i = cnt + tid; i < EDGE_CAP; i += TPB) sDall[i] = 0.f;
    __syncthreads();
    if (tid == 0) {
        int s = 0;
        for (int a = 0; a < A_ATOMS; ++a) { sPtr[a] = s; s += sDeg[a]; }
        sPtr[A_ATOMS] = s;
    }
    __syncthreads();
    const int NB = (cnt + EB - 1) / EB;
    // ordered CSR fill + per-batch windows (thread a owns its segment)
    if (tid < A_ATOMS) {
        const int ps = sPtr[tid];
        int pos = ps;
        for (int i = 0; i < cnt; ++i) {
            unsigned pe = sEdge[i];
            int a0l = (pe >> 6) & 63, a1l = pe & 63;
            if (a0l == tid) sCsr[pos++] = (unsigned short)((a1l << 10) | i);
            if (a1l == tid) sCsr[pos++] = (unsigned short)((a0l << 10) | i);
        }
        int p = ps;
        for (int b = 0; b <= NB; ++b) {
            const int lim = b * EB;
            while (p < pos && (int)(sCsr[p] & 1023) < lim) ++p;
            sWin[tid * (NBMAX + 1) + b] = (unsigned short)p;
        }
    }

    // f32 delta accumulator in fixed MFMA lane layout (output-accuracy path)
    f32x4 dsum[3][2];
#pragma unroll
    for (int mt = 0; mt < 3; ++mt)
#pragma unroll
        for (int j = 0; j < 2; ++j) dsum[mt][j] = (f32x4){0.f, 0.f, 0.f, 0.f};

    for (int l = 0; l < NLAYERS; ++l) {
        __syncthreads();
        // ---- M1: sBb = bf16(r @ Wn + bn)
        {
            f32x4 acc[3][2];
            mfma_dense8b(sRb, WT + ((size_t)(0 * 4 + l) << 16), acc, lane, wv);
            mfma_wb8b<0>(acc, sBb, bn + l * D, lane, wv);
        }
        __syncthreads();
        // ---- edge phase: balanced 2-barrier pipeline, batches of 32
        float4 agg[5];
#pragma unroll
        for (int k = 0; k < 5; ++k) agg[k] = make_float4(0.f, 0.f, 0.f, 0.f);
        {
            const bshort8 bf0 = *(const bshort8*)&WT2[(size_t)l * 8192 + ((2 * wv + 0) * 16 + fr) * 32 + g8];
            const bshort8 bf1 = *(const bshort8*)&WT2[(size_t)l * 8192 + ((2 * wv + 1) * 16 + fr) * 32 + g8];
            const float bb0 = be2[l * D + (2 * wv + 0) * 16 + fr];
            const float bb1 = be2[l * D + (2 * wv + 1) * 16 + fr];
            const bshort8 bfX = *(const bshort8*)&We1T[(size_t)l * 1024 + (ttx * 16 + fr) * 32 + g8];
            const float bbX = be1[l * NG + ttx * 16 + fr];

            // prologue: X2(0) -> sHb[0] (waves 0..3)
            if (wv < 4 && NB > 0) {
                const float dd = sDall[mtx * 16 + fr];
                union { bshort8 v; unsigned u[4]; } ua;
#pragma unroll
                for (int j = 0; j < 4; ++j) {
                    const float u0 = dd - (float)(g8 + 2 * j + 0);
                    const float u1 = dd - (float)(g8 + 2 * j + 1);
                    ua.u[j] = pkbf(expf(-0.5f * u0 * u0), expf(-0.5f * u1 * u1));
                }
                f32x4 c = (f32x4){0.f, 0.f, 0.f, 0.f};
                c = __builtin_amdgcn_mfma_f32_16x16x32_bf16(ua.v, bfX, c, 0, 0, 0);
#pragma unroll
                for (int reg = 0; reg < 4; ++reg) {
                    const int erow = mtx * 16 + fg * 4 + reg;
                    sHb[0][erow * SHBP + ttx * 16 + fr] = f2bf(sspf(c[reg] + bbX));
                }
            }
            __syncthreads();
            for (int b = 0; b < NB; ++b) {
                const int base = b * EB;
                // ---- phase1: P4(b) all waves; X2(b+1) waves 0..3
                {
                    const short* __restrict__ hb = sHb[b & 1];
#pragma unroll
                    for (int mt = 0; mt < 2; ++mt) {
                        union { bshort8 v; short4 s[2]; } af;
                        af.s[0] = *(const short4*)&hb[(mt * 16 + fr) * SHBP + g8];
                        af.s[1] = *(const short4*)&hb[(mt * 16 + fr) * SHBP + g8 + 4];
                        f32x4 c0 = (f32x4){0.f, 0.f, 0.f, 0.f};
                        c0 = __builtin_amdgcn_mfma_f32_16x16x32_bf16(af.v, bf0, c0, 0, 0, 0);
                        f32x4 c1 = (f32x4){0.f, 0.f, 0.f, 0.f};
                        c1 = __builtin_amdgcn_mfma_f32_16x16x32_bf16(af.v, bf1, c1, 0, 0, 0);
#pragma unroll
                        for (int reg = 0; reg < 4; ++reg) {
                            const int erow = mt * 16 + fg * 4 + reg;
                            sEFs[erow * SEFP + (2 * wv + 0) * 16 + fr] = f2bf(c0[reg] + bb0);
                            sEFs[erow * SEFP + (2 * wv + 1) * 16 + fr] = f2bf(c1[reg] + bb1);
                        }
                    }
                }
                if (wv < 4 && b + 1 < NB) {
                    short* __restrict__ hb = sHb[(b + 1) & 1];
                    const float dd = sDall[(b + 1) * EB + mtx * 16 + fr];
                    union { bshort8 v; unsigned u[4]; } ua;
#pragma unroll
                    for (int j = 0; j < 4; ++j) {
                        const float u0 = dd - (float)(g8 + 2 * j + 0);
                        const float u1 = dd - (float)(g8 + 2 * j + 1);
                        ua.u[j] = pkbf(expf(-0.5f * u0 * u0), expf(-0.5f * u1 * u1));
                    }
                    f32x4 c = (f32x4){0.f, 0.f, 0.f, 0.f};
                    c = __builtin_amdgcn_mfma_f32_16x16x32_bf16(ua.v, bfX, c, 0, 0, 0);
#pragma unroll
                    for (int reg = 0; reg < 4; ++reg) {
                        const int erow = mtx * 16 + fg * 4 + reg;
                        hb[erow * SHBP + ttx * 16 + fr] = f2bf(sspf(c[reg] + bbX));
                    }
                }
                __syncthreads();
                // ---- phase2: P5 counted gathers (wave owns rows 5wv..5wv+4)
#pragma unroll
                for (int k = 0; k < 5; ++k) {
                    const int row = wv * 5 + k;
                    const int st = (int)sWin[row * (NBMAX + 1) + b];
                    const int en = (int)sWin[row * (NBMAX + 1) + b + 1];
                    for (int i = st; i < en; ++i) {
                        const int ent = (int)sCsr[i];
                        const int e = ent & 1023, src = ent >> 10;
                        const short4 f4 = *(const short4*)&sEFs[(e - base) * SEFP + c4];
                        const short4 r4 = *(const short4*)&sBb[SWZ(src, c4)];
                        agg[k].x = fmaf(b2f(f4.x), b2f(r4.x), agg[k].x);
                        agg[k].y = fmaf(b2f(f4.y), b2f(r4.y), agg[k].y);
                        agg[k].z = fmaf(b2f(f4.z), b2f(r4.z), agg[k].z);
                        agg[k].w = fmaf(b2f(f4.w), b2f(r4.w), agg[k].w);
                    }
                }
                __syncthreads();
            }
        }
        // agg -> sBb (rn dead)
#pragma unroll
        for (int k = 0; k < 5; ++k) {
            uint2 p;
            p.x = pkbf(agg[k].x, agg[k].y);
            p.y = pkbf(agg[k].z, agg[k].w);
            *(uint2*)&sBb[SWZ(wv * 5 + k, c4)] = p;
        }
        __syncthreads();
        // ---- M2: sBb = bf16(ssp(agg @ Wu1 + bu1))  (in-place: sync between acc and wb)
        {
            f32x4 acc[3][2];
            mfma_dense8b(sBb, WT + ((size_t)(1 * 4 + l) << 16), acc, lane, wv);
            __syncthreads();
            mfma_wb8b<1>(acc, sBb, bu1 + l * D, lane, wv);
        }
        __syncthreads();
        // ---- M3: delta = t @ Wu2 + bu2; dsum += delta (f32); r_bf16 += delta
        {
            f32x4 acc[3][2];
            mfma_dense8b(sBb, WT + ((size_t)(2 * 4 + l) << 16), acc, lane, wv);
            const int cc = lane & 15, g = lane >> 4, cr = g * 4;
#pragma unroll
            for (int j = 0; j < 2; ++j) {
                const int col = (wv * 2 + j) * 16 + cc;
                const float bv = bu2[l * D + col];
#pragma unroll
                for (int mt = 0; mt < 3; ++mt) {
                    if (mt == 2 && g >= 2) continue;
#pragma unroll
                    for (int reg = 0; reg < 4; ++reg) {
                        const int row = mt * 16 + cr + reg;
                        float v = acc[mt][j][reg] + bv;
                        dsum[mt][j][reg] += v;
                        const int idx = SWZ(row, col);
                        sRb[idx] = f2bf(b2f(sRb[idx]) + v);
                    }
                }
            }
        }
    }
    // ---- output: colsum = sum over atoms of (emb + sum of deltas), all f32
    __syncthreads();
    if (tid < D) colsum[tid] = 0.f;
    __syncthreads();
    {
        const int cc = lane & 15, g = lane >> 4;
#pragma unroll
        for (int j = 0; j < 2; ++j) {
            const int col = (wv * 2 + j) * 16 + cc;
            float s = 0.f;
#pragma unroll
            for (int mt = 0; mt < 3; ++mt) {
                if (mt == 2 && g >= 2) continue;
#pragma unroll
                for (int reg = 0; reg < 4; ++reg) s += dsum[mt][j][reg];
            }
            atomicAdd(&colsum[col], s);
        }
        atomicAdd(&colsum[tid & 255], embsum);
    }
    __syncthreads();
    if (tid < D) conf_fp[conf * D + tid] = colsum[tid];
}

// ---------------- per-conformer molecular MLP + Boltzmann-weighted reduce ----------------
__global__ __launch_bounds__(512) void k_mol(
    const float* __restrict__ conf_fp,
    const float* __restrict__ Wm1, const float* __restrict__ bm1,
    const float* __restrict__ Wm2, const float* __restrict__ bm2,
    const float* __restrict__ boltz, float* __restrict__ mol_fp)
{
    __shared__ float cf[D];
    __shared__ float t[H_MOL];
    const int conf = blockIdx.x;
    const int tid = threadIdx.x;
    if (tid < D) cf[tid] = conf_fp[conf * D + tid];
    __syncthreads();
    if (tid < H_MOL) {
        float s = bm1[tid];
        for (int k = 0; k < D; k += 4) {
            const float4 v = *(const float4*)&cf[k];
            s = fmaf(v.x, Wm1[(k + 0) * H_MOL + tid], s);
            s = fmaf(v.y, Wm1[(k + 1) * H_MOL + tid], s);
            s = fmaf(v.z, Wm1[(k + 2) * H_MOL + tid], s);
            s = fmaf(v.w, Wm1[(k + 3) * H_MOL + tid], s);
        }
        t[tid] = sspf(s);
    }
    __syncthreads();
    {
        const int m = tid;
        float s = bm2[m];
        for (int h = 0; h < H_MOL; h += 4) {
            const float4 v = *(const float4*)&t[h];
            s = fmaf(v.x, Wm2[(h + 0) * MOLB + m], s);
            s = fmaf(v.y, Wm2[(h + 1) * MOLB + m], s);
            s = fmaf(v.z, Wm2[(h + 2) * MOLB + m], s);
            s = fmaf(v.w, Wm2[(h + 3) * MOLB + m], s);
        }
        atomicAdd(&mol_fp[(conf / N_CONFS_PER) * MOLB + m], s * boltz[conf]);
    }
}

// ---------------- final readout MLP + sigmoid ----------------
__global__ __launch_bounds__(256) void k_final(
    const float* __restrict__ mol_fp,
    const float* __restrict__ Wr1, const float* __restrict__ br1,
    const float* __restrict__ Wr2, const float* __restrict__ br2,
    float* __restrict__ out)
{
    __shared__ float mf[MOLB];
    __shared__ float t2[D];
    __shared__ float red[4];
    const int mol = blockIdx.x, tid = threadIdx.x;
    mf[tid]       = mol_fp[mol * MOLB + tid];
    mf[tid + 256] = mol_fp[mol * MOLB + tid + 256];
    __syncthreads();
    {
        float s = br1[tid];
        for (int k = 0; k < MOLB; k += 4) {
            const float4 v = *(const float4*)&mf[k];
            s = fmaf(v.x, Wr1[(k + 0) * D + tid], s);
            s = fmaf(v.y, Wr1[(k + 1) * D + tid], s);
            s = fmaf(v.z, Wr1[(k + 2) * D + tid], s);
            s = fmaf(v.w, Wr1[(k + 3) * D + tid], s);
        }
        t2[tid] = sspf(s);
    }
    __syncthreads();
    float p = t2[tid] * Wr2[tid];
#pragma unroll
    for (int o = 32; o > 0; o >>= 1) p += __shfl_down(p, o);
    if ((tid & 63) == 0) red[tid >> 6] = p;
    __syncthreads();
    if (tid == 0) {
        float logit = red[0] + red[1] + red[2] + red[3] + br2[0];
        out[mol] = 1.f / (1.f + expf(-logit));
    }
}

extern "C" void kernel_launch(void* const* d_in, const int* in_sizes, int n_in,
                              void* d_out, int out_size, void* d_ws, size_t ws_size,
                              hipStream_t stream)
{
    const int*   z     = (const int*)d_in[0];
    const float* xyz   = (const float*)d_in[1];
    const int*   nbr   = (const int*)d_in[2];
    const float* boltz = (const float*)d_in[3];
    const float* emb   = (const float*)d_in[4];
    const float* We1   = (const float*)d_in[5];
    const float* be1   = (const float*)d_in[6];
    const float* We2   = (const float*)d_in[7];
    const float* be2   = (const float*)d_in[8];
    const float* Wn    = (const float*)d_in[9];
    const float* bn    = (const float*)d_in[10];
    const float* Wu1   = (const float*)d_in[11];
    const float* bu1   = (const float*)d_in[12];
    const float* Wu2   = (const float*)d_in[13];
    const float* bu2   = (const float*)d_in[14];
    const float* Wm1   = (const float*)d_in[15];
    const float* bm1   = (const float*)d_in[16];
    const float* Wm2   = (const float*)d_in[17];
    const float* bm2   = (const float*)d_in[18];
    const float* Wr1   = (const float*)d_in[19];
    const float* br1   = (const float*)d_in[20];
    const float* Wr2   = (const float*)d_in[21];
    const float* br2   = (const float*)d_in[22];

    char* ws = (char*)d_ws;
    unsigned* cursors        = (unsigned*)ws;                   // 2560 B
    float*    mol_fp         = (float*)(ws + 2560);             // 131072 B -> 133632
    unsigned* esort          = (unsigned*)(ws + 133632);        // 2621440 B -> 2755072
    float*    conf_fp        = (float*)(ws + 2755072);          // 655360 B -> 3410432
    __hip_bfloat16* WT       = (__hip_bfloat16*)(ws + 3410432); // 1572864 B -> 4983296
    __hip_bfloat16* WT2      = (__hip_bfloat16*)(ws + 4983296); // 65536 B -> 5048832
    __hip_bfloat16* We1T     = (__hip_bfloat16*)(ws + 5048832); // 8192 B -> 5057024

    hipMemsetAsync(cursors, 0, 2560 + 131072, stream);          // cursors + mol_fp
    k_prep<<<3072, 256, 0, stream>>>(Wn, Wu1, Wu2, WT);
    k_prep2<<<144, 256, 0, stream>>>(We2, We1, WT2, We1T);
    k_scatter<<<(N_EDGES + 255) / 256, 256, 0, stream>>>(nbr, cursors, esort);
    k_main<<<N_CONFS, TPB, 0, stream>>>(z, xyz, emb, be1, be2, bn,
                                        bu1, bu2, WT, WT2, We1T, cursors, esort, conf_fp);
    k_mol<<<N_CONFS, 512, 0, stream>>>(conf_fp, Wm1, bm1, Wm2, bm2, boltz, mol_fp);
    k_final<<<N_MOLS, 256, 0, stream>>>(mol_fp, Wr1, br1, Wr2, br2, (float*)d_out);
}

// Round 13
// 1131.076 us; speedup vs baseline: 1.1553x; 1.0006x over previous
//
#include <hip/hip_runtime.h>
#include <hip/hip_bf16.h>

#define N_MOLS      64
#define N_CONFS_PER 10
#define A_ATOMS     40
#define N_CONFS     640
#define N_ATOMS     25600
#define N_EDGES     409600
#define D           256
#define NG          32
#define NLAYERS     4
#define MOLB        512
#define H_MOL       384
#define EDGE_CAP    1024
#define EB          32    // edge batch
#define NBMAX       32    // max batches (EDGE_CAP/EB)
#define SHBP        36    // sHb row stride (halfwords)
#define SEFP        260   // sEFs row stride (halfwords)
#define SBH         256   // bf16 tile row stride (halfwords), XOR-swizzled
#define TPB         512   // 8 waves

typedef __attribute__((ext_vector_type(8))) short bshort8;
typedef __attribute__((ext_vector_type(4))) float f32x4;

// swizzled halfword index into a [48][SBH] bf16 tile (conflict-free b128 A-frag reads)
#define SWZ(row, hw) (((row) << 8) + ((hw) ^ (((row) & 7) << 3)))

__device__ __forceinline__ float sspf(float x) {
    return fmaxf(x, 0.f) + log1pf(expf(-fabsf(x))) - 0.69314718055994531f;
}
__device__ __forceinline__ float b2f(short s) {
    union { unsigned u; float f; } u;
    u.u = ((unsigned)(unsigned short)s) << 16;
    return u.f;
}
__device__ __forceinline__ short f2bf(float x) {
    return (short)(unsigned short)((__float_as_uint(x) + 0x8000u) >> 16);
}
__device__ __forceinline__ unsigned pkbf(float lo_e, float hi_e) {
    return __builtin_amdgcn_perm(__float_as_uint(hi_e) + 0x8000u,
                                 __float_as_uint(lo_e) + 0x8000u, 0x07060302u);
}

// ---------------- weight prep: dense W[l][k][n] fp32 -> WT[mat][l][n][k] bf16 ----------------
__global__ __launch_bounds__(256) void k_prep(const float* __restrict__ Wn,
                                              const float* __restrict__ Wu1,
                                              const float* __restrict__ Wu2,
                                              __hip_bfloat16* __restrict__ WT) {
    int idx = blockIdx.x * 256 + threadIdx.x;       // 3*4*256*256
    int k = idx & 255;
    int n = (idx >> 8) & 255;
    int l = (idx >> 16) & 3;
    int mat = idx >> 18;
    const float* src = (mat == 0) ? Wn : (mat == 1) ? Wu1 : Wu2;
    WT[idx] = __float2bfloat16(src[((size_t)l * 256 + k) * 256 + n]);
}

// WT2[l][n][k] bf16 from We2[l][k][n]; We1T[l][t][m] bf16 from We1[l][m][t]
__global__ __launch_bounds__(256) void k_prep2(const float* __restrict__ We2,
                                               const float* __restrict__ We1,
                                               __hip_bfloat16* __restrict__ WT2,
                                               __hip_bfloat16* __restrict__ We1T) {
    int idx = blockIdx.x * 256 + threadIdx.x;       // 32768 + 4096
    if (idx < 32768) {
        int k = idx & 31;
        int n = (idx >> 5) & 255;
        int l = idx >> 13;
        WT2[idx] = __float2bfloat16(We2[((size_t)l * 32 + k) * 256 + n]);
    } else {
        int j = idx - 32768;
        int m = j & 31;
        int t = (j >> 5) & 31;
        int l = j >> 10;
        We1T[j] = __float2bfloat16(We1[((size_t)l * 32 + m) * 32 + t]);
    }
}

// ---------------- edge bucketing by conformer ----------------
__global__ __launch_bounds__(256) void k_scatter(const int* __restrict__ nbr,
                                                 unsigned* __restrict__ cursors,
                                                 unsigned* __restrict__ esort) {
    int e = blockIdx.x * 256 + threadIdx.x;
    if (e >= N_EDGES) return;
    int a0 = nbr[2 * e], a1 = nbr[2 * e + 1];
    int conf = a0 / A_ATOMS;
    int a0l = a0 - conf * A_ATOMS;
    int a1l = a1 - conf * A_ATOMS;
    unsigned r = atomicAdd(&cursors[conf], 1u);
    if (r < EDGE_CAP) esort[conf * EDGE_CAP + r] = (unsigned)((a0l << 6) | a1l);
}

// dense MFMA from bf16 swizzled tile: wave -> 3 m-tiles x n-tiles {2wv, 2wv+1}
__device__ __forceinline__ void mfma_dense8b(const short* __restrict__ src,
                                             const __hip_bfloat16* __restrict__ WT,
                                             f32x4 acc[3][2], int lane, int wv) {
    const int r = lane & 15, g = lane >> 4;
#pragma unroll
    for (int mt = 0; mt < 3; ++mt)
#pragma unroll
        for (int j = 0; j < 2; ++j) acc[mt][j] = (f32x4){0.f, 0.f, 0.f, 0.f};
#pragma unroll 2
    for (int kt = 0; kt < 8; ++kt) {
        const int ko = kt * 32 + g * 8;
        bshort8 a0 = *(const bshort8*)&src[SWZ(0 * 16 + r, ko)];
        bshort8 a1 = *(const bshort8*)&src[SWZ(1 * 16 + r, ko)];
        bshort8 a2 = *(const bshort8*)&src[SWZ(2 * 16 + r, ko)];
#pragma unroll
        for (int j = 0; j < 2; ++j) {
            const int nt = wv * 2 + j;
            bshort8 b = *(const bshort8*)&WT[(nt * 16 + r) * 256 + ko];
            acc[0][j] = __builtin_amdgcn_mfma_f32_16x16x32_bf16(a0, b, acc[0][j], 0, 0, 0);
            acc[1][j] = __builtin_amdgcn_mfma_f32_16x16x32_bf16(a1, b, acc[1][j], 0, 0, 0);
            acc[2][j] = __builtin_amdgcn_mfma_f32_16x16x32_bf16(a2, b, acc[2][j], 0, 0, 0);
        }
    }
}

// writeback: MODE 0: dst16 = bf16(acc+bias) ; 1: dst16 = bf16(ssp(acc+bias))
template <int MODE>
__device__ __forceinline__ void mfma_wb8b(const f32x4 acc[3][2], short* __restrict__ dst16,
                                          const float* __restrict__ bias, int lane, int wv) {
    const int cc = lane & 15, g = lane >> 4;
    const int cr = g * 4;
#pragma unroll
    for (int j = 0; j < 2; ++j) {
        const int col = (wv * 2 + j) * 16 + cc;
        const float bv = bias[col];
#pragma unroll
        for (int mt = 0; mt < 3; ++mt) {
            if (mt == 2 && g >= 2) continue;   // rows 40..47 are padding
#pragma unroll
            for (int reg = 0; reg < 4; ++reg) {
                const int row = mt * 16 + cr + reg;
                float v = acc[mt][j][reg] + bv;
                if (MODE == 1) v = sspf(v);
                dst16[SWZ(row, col)] = f2bf(v);
            }
        }
    }
}

// ---------------- main per-conformer kernel: 512 threads, 8 waves, 2 blocks/CU ----------------
__global__ __launch_bounds__(TPB, 4) void k_main(
    const int* __restrict__ z, const float* __restrict__ xyz,
    const float* __restrict__ emb,
    const float* __restrict__ be1, const float* __restrict__ be2,
    const float* __restrict__ bn,
    const float* __restrict__ bu1, const float* __restrict__ bu2,
    const __hip_bfloat16* __restrict__ WT,
    const __hip_bfloat16* __restrict__ WT2,
    const __hip_bfloat16* __restrict__ We1T,
    const unsigned* __restrict__ cursors, const unsigned* __restrict__ esort,
    float* __restrict__ conf_fp)
{
    __shared__ short sRb[48 * SBH];           // r bf16, swizzled (24.6KB)
    __shared__ short sBb[48 * SBH];           // rn -> agg -> t bf16, swizzled (24.6KB)
    __shared__ __align__(16) char uEFbuf[EB * SEFP * 2];  // 16.6KB: sEFs | setup{xyz,z,deg} | colsum
    __shared__ __align__(16) char sHbBuf[2 * EB * SHBP * 2]; // 4.6KB: sHb | setup sEdge
    __shared__ float sDall[EDGE_CAP];         // scaled distances, zero-padded (4KB)
    __shared__ unsigned short sCsr[2 * EDGE_CAP];          // (src<<10)|edge (4KB)
    __shared__ unsigned short sWin[A_ATOMS * (NBMAX + 1)]; // per-(atom,batch) cursor (2.6KB)
    __shared__ int sPtr[A_ATOMS + 1];

    short* sEFs = (short*)uEFbuf;
    float* colsum = (float*)uEFbuf;
    float (*sXYZ)[3] = (float(*)[3])uEFbuf;       // setup alias
    int* sZ   = (int*)(uEFbuf + 480);             // setup alias
    int* sDeg = (int*)(uEFbuf + 640);             // setup alias
    short (*sHb)[EB * SHBP] = (short(*)[EB * SHBP])sHbBuf;
    unsigned* sEdge = (unsigned*)sHbBuf;          // setup alias (4KB <= 4.6KB)

    const int tid  = threadIdx.x;
    const int lane = tid & 63;
    const int wv   = tid >> 6;        // 0..7
    const int c4   = lane << 2;
    const int conf = blockIdx.x;
    const int fr = lane & 15, fg = lane >> 4, g8 = (lane >> 4) << 3;
    const int mtx = wv & 1;           // X2 m-tile (waves 0..3)
    const int ttx = (wv >> 1) & 1;    // X2 t-tile

    if (tid < A_ATOMS) {
        int ga = conf * A_ATOMS + tid;
        sZ[tid] = z[ga];
        sXYZ[tid][0] = xyz[ga * 3 + 0];
        sXYZ[tid][1] = xyz[ga * 3 + 1];
        sXYZ[tid][2] = xyz[ga * 3 + 2];
        sDeg[tid] = 0;
    }
    for (int i = tid; i < 8 * SBH; i += TPB) {   // zero bf16 pad rows 40..47
        sRb[40 * SBH + i] = 0;
        sBb[40 * SBH + i] = 0;
    }
    __syncthreads();
    float embsum = 0.f;
    {   // embedding init: bf16 r + f32 emb partial (rows q::2, col c)
        const int c = tid & 255, q = tid >> 8;
        for (int aa = q; aa < A_ATOMS; aa += 2) {
            float v = emb[sZ[aa] * D + c];
            embsum += v;
            sRb[SWZ(aa, c)] = f2bf(v);
        }
    }
    int cnt = (int)cursors[conf];
    if (cnt > EDGE_CAP) cnt = EDGE_CAP;
    const unsigned* eptr = esort + conf * EDGE_CAP;
    for (int i = tid; i < cnt; i += TPB) {
        unsigned pe = eptr[i];
        sEdge[i] = pe;
        int a0l = (pe >> 6) & 63, a1l = pe & 63;
        float dx = sXYZ[a0l][0] - sXYZ[a1l][0];
        float dy = sXYZ[a0l][1] - sXYZ[a1l][1];
        float dz = sXYZ[a0l][2] - sXYZ[a1l][2];
        sDall[i] = sqrtf(dx * dx + dy * dy + dz * dz) * (31.0f / 5.0f);
        atomicAdd(&sDeg[a0l], 1);
        atomicAdd(&sDeg[a1l], 1);
    }
    for (int i = cnt + tid; i < EDGE_CAP; i += TPB) sDall[i] = 0.f;
    __syncthreads();
    if (tid == 0) {
        int s = 0;
        for (int a = 0; a < A_ATOMS; ++a) { sPtr[a] = s; s += sDeg[a]; }
        sPtr[A_ATOMS] = s;
    }
    __syncthreads();
    const int NB = (cnt + EB - 1) / EB;
    // ordered CSR fill + per-batch windows (thread a owns its segment)
    if (tid < A_ATOMS) {
        const int ps = sPtr[tid];
        int pos = ps;
        for (int i = 0; i < cnt; ++i) {
            unsigned pe = sEdge[i];
            int a0l = (pe >> 6) & 63, a1l = pe & 63;
            if (a0l == tid) sCsr[pos++] = (unsigned short)((a1l << 10) | i);
            if (a1l == tid) sCsr[pos++] = (unsigned short)((a0l << 10) | i);
        }
        int p = ps;
        for (int b = 0; b <= NB; ++b) {
            const int lim = b * EB;
            while (p < pos && (int)(sCsr[p] & 1023) < lim) ++p;
            sWin[tid * (NBMAX + 1) + b] = (unsigned short)p;
        }
    }

    // f32 delta accumulator in fixed MFMA lane layout (output-accuracy path)
    f32x4 dsum[3][2];
#pragma unroll
    for (int mt = 0; mt < 3; ++mt)
#pragma unroll
        for (int j = 0; j < 2; ++j) dsum[mt][j] = (f32x4){0.f, 0.f, 0.f, 0.f};

    for (int l = 0; l < NLAYERS; ++l) {
        __syncthreads();
        // ---- M1: sBb = bf16(r @ Wn + bn)
        {
            f32x4 acc[3][2];
            mfma_dense8b(sRb, WT + ((size_t)(0 * 4 + l) << 16), acc, lane, wv);
            mfma_wb8b<0>(acc, sBb, bn + l * D, lane, wv);
        }
        __syncthreads();
        // ---- edge phase: balanced 2-barrier pipeline, batches of 32
        float4 agg[5];
#pragma unroll
        for (int k = 0; k < 5; ++k) agg[k] = make_float4(0.f, 0.f, 0.f, 0.f);
        {
            const bshort8 bf0 = *(const bshort8*)&WT2[(size_t)l * 8192 + ((2 * wv + 0) * 16 + fr) * 32 + g8];
            const bshort8 bf1 = *(const bshort8*)&WT2[(size_t)l * 8192 + ((2 * wv + 1) * 16 + fr) * 32 + g8];
            const float bb0 = be2[l * D + (2 * wv + 0) * 16 + fr];
            const float bb1 = be2[l * D + (2 * wv + 1) * 16 + fr];
            const bshort8 bfX = *(const bshort8*)&We1T[(size_t)l * 1024 + (ttx * 16 + fr) * 32 + g8];
            const float bbX = be1[l * NG + ttx * 16 + fr];

            // prologue: X2(0) -> sHb[0] (waves 0..3)
            if (wv < 4 && NB > 0) {
                const float dd = sDall[mtx * 16 + fr];
                union { bshort8 v; unsigned u[4]; } ua;
#pragma unroll
                for (int j = 0; j < 4; ++j) {
                    const float u0 = dd - (float)(g8 + 2 * j + 0);
                    const float u1 = dd - (float)(g8 + 2 * j + 1);
                    ua.u[j] = pkbf(expf(-0.5f * u0 * u0), expf(-0.5f * u1 * u1));
                }
                f32x4 c = (f32x4){0.f, 0.f, 0.f, 0.f};
                c = __builtin_amdgcn_mfma_f32_16x16x32_bf16(ua.v, bfX, c, 0, 0, 0);
#pragma unroll
                for (int reg = 0; reg < 4; ++reg) {
                    const int erow = mtx * 16 + fg * 4 + reg;
                    sHb[0][erow * SHBP + ttx * 16 + fr] = f2bf(sspf(c[reg] + bbX));
                }
            }
            __syncthreads();
            for (int b = 0; b < NB; ++b) {
                const int base = b * EB;
                // ---- phase1: P4(b) all waves; X2(b+1) waves 0..3
                {
                    const short* __restrict__ hb = sHb[b & 1];
#pragma unroll
                    for (int mt = 0; mt < 2; ++mt) {
                        union { bshort8 v; short4 s[2]; } af;
                        af.s[0] = *(const short4*)&hb[(mt * 16 + fr) * SHBP + g8];
                        af.s[1] = *(const short4*)&hb[(mt * 16 + fr) * SHBP + g8 + 4];
                        f32x4 c0 = (f32x4){0.f, 0.f, 0.f, 0.f};
                        c0 = __builtin_amdgcn_mfma_f32_16x16x32_bf16(af.v, bf0, c0, 0, 0, 0);
                        f32x4 c1 = (f32x4){0.f, 0.f, 0.f, 0.f};
                        c1 = __builtin_amdgcn_mfma_f32_16x16x32_bf16(af.v, bf1, c1, 0, 0, 0);
#pragma unroll
                        for (int reg = 0; reg < 4; ++reg) {
                            const int erow = mt * 16 + fg * 4 + reg;
                            sEFs[erow * SEFP + (2 * wv + 0) * 16 + fr] = f2bf(c0[reg] + bb0);
                            sEFs[erow * SEFP + (2 * wv + 1) * 16 + fr] = f2bf(c1[reg] + bb1);
                        }
                    }
                }
                if (wv < 4 && b + 1 < NB) {
                    short* __restrict__ hb = sHb[(b + 1) & 1];
                    const float dd = sDall[(b + 1) * EB + mtx * 16 + fr];
                    union { bshort8 v; unsigned u[4]; } ua;
#pragma unroll
                    for (int j = 0; j < 4; ++j) {
                        const float u0 = dd - (float)(g8 + 2 * j + 0);
                        const float u1 = dd - (float)(g8 + 2 * j + 1);
                        ua.u[j] = pkbf(expf(-0.5f * u0 * u0), expf(-0.5f * u1 * u1));
                    }
                    f32x4 c = (f32x4){0.f, 0.f, 0.f, 0.f};
                    c = __builtin_amdgcn_mfma_f32_16x16x32_bf16(ua.v, bfX, c, 0, 0, 0);
#pragma unroll
                    for (int reg = 0; reg < 4; ++reg) {
                        const int erow = mtx * 16 + fg * 4 + reg;
                        hb[erow * SHBP + ttx * 16 + fr] = f2bf(sspf(c[reg] + bbX));
                    }
                }
                __syncthreads();
                // ---- phase2: P5 counted gathers (wave owns rows 5wv..5wv+4)
#pragma unroll
                for (int k = 0; k < 5; ++k) {
                    const int row = wv * 5 + k;
                    const int st = (int)sWin[row * (NBMAX + 1) + b];
                    const int en = (int)sWin[row * (NBMAX + 1) + b + 1];
                    for (int i = st; i < en; ++i) {
                        const int ent = (int)sCsr[i];
                        const int e = ent & 1023, src = ent >> 10;
                        const short4 f4 = *(const short4*)&sEFs[(e - base) * SEFP + c4];
                        const short4 r4 = *(const short4*)&sBb[SWZ(src, c4)];
                        agg[k].x = fmaf(b2f(f4.x), b2f(r4.x), agg[k].x);
                        agg[k].y = fmaf(b2f(f4.y), b2f(r4.y), agg[k].y);
                        agg[k].z = fmaf(b2f(f4.z), b2f(r4.z), agg[k].z);
                        agg[k].w = fmaf(b2f(f4.w), b2f(r4.w), agg[k].w);
                    }
                }
                __syncthreads();
            }
        }
        // agg -> sBb (rn dead)
#pragma unroll
        for (int k = 0; k < 5; ++k) {
            uint2 p;
            p.x = pkbf(agg[k].x, agg[k].y);
            p.y = pkbf(agg[k].z, agg[k].w);
            *(uint2*)&sBb[SWZ(wv * 5 + k, c4)] = p;
        }
        __syncthreads();
        // ---- M2: sBb = bf16(ssp(agg @ Wu1 + bu1))  (in-place: sync between acc and wb)
        {
            f32x4 acc[3][2];
            mfma_dense8b(sBb, WT + ((size_t)(1 * 4 + l) << 16), acc, lane, wv);
            __syncthreads();
            mfma_wb8b<1>(acc, sBb, bu1 + l * D, lane, wv);
        }
        __syncthreads();
        // ---- M3: delta = t @ Wu2 + bu2; dsum += delta (f32); r_bf16 += delta
        {
            f32x4 acc[3][2];
            mfma_dense8b(sBb, WT + ((size_t)(2 * 4 + l) << 16), acc, lane, wv);
            const int cc = lane & 15, g = lane >> 4, cr = g * 4;
#pragma unroll
            for (int j = 0; j < 2; ++j) {
                const int col = (wv * 2 + j) * 16 + cc;
                const float bv = bu2[l * D + col];
#pragma unroll
                for (int mt = 0; mt < 3; ++mt) {
                    if (mt == 2 && g >= 2) continue;
#pragma unroll
                    for (int reg = 0; reg < 4; ++reg) {
                        const int row = mt * 16 + cr + reg;
                        float v = acc[mt][j][reg] + bv;
                        dsum[mt][j][reg] += v;
                        const int idx = SWZ(row, col);
                        sRb[idx] = f2bf(b2f(sRb[idx]) + v);
                    }
                }
            }
        }
    }
    // ---- output: colsum = sum over atoms of (emb + sum of deltas), all f32
    __syncthreads();
    if (tid < D) colsum[tid] = 0.f;
    __syncthreads();
    {
        const int cc = lane & 15, g = lane >> 4;
#pragma unroll
        for (int j = 0; j < 2; ++j) {
            const int col = (wv * 2 + j) * 16 + cc;
            float s = 0.f;
#pragma unroll
            for (int mt = 0; mt < 3; ++mt) {
                if (mt == 2 && g >= 2) continue;
#pragma unroll
                for (int reg = 0; reg < 4; ++reg) s += dsum[mt][j][reg];
            }
            atomicAdd(&colsum[col], s);
        }
        atomicAdd(&colsum[tid & 255], embsum);
    }
    __syncthreads();
    if (tid < D) conf_fp[conf * D + tid] = colsum[tid];
}

// ---------------- per-conformer molecular MLP + Boltzmann-weighted reduce ----------------
__global__ __launch_bounds__(512) void k_mol(
    const float* __restrict__ conf_fp,
    const float* __restrict__ Wm1, const float* __restrict__ bm1,
    const float* __restrict__ Wm2, const float* __restrict__ bm2,
    const float* __restrict__ boltz, float* __restrict__ mol_fp)
{
    __shared__ float cf[D];
    __shared__ float t[H_MOL];
    const int conf = blockIdx.x;
    const int tid = threadIdx.x;
    if (tid < D) cf[tid] = conf_fp[conf * D + tid];
    __syncthreads();
    if (tid < H_MOL) {
        float s = bm1[tid];
        for (int k = 0; k < D; k += 4) {
            const float4 v = *(const float4*)&cf[k];
            s = fmaf(v.x, Wm1[(k + 0) * H_MOL + tid], s);
            s = fmaf(v.y, Wm1[(k + 1) * H_MOL + tid], s);
            s = fmaf(v.z, Wm1[(k + 2) * H_MOL + tid], s);
            s = fmaf(v.w, Wm1[(k + 3) * H_MOL + tid], s);
        }
        t[tid] = sspf(s);
    }
    __syncthreads();
    {
        const int m = tid;
        float s = bm2[m];
        for (int h = 0; h < H_MOL; h += 4) {
            const float4 v = *(const float4*)&t[h];
            s = fmaf(v.x, Wm2[(h + 0) * MOLB + m], s);
            s = fmaf(v.y, Wm2[(h + 1) * MOLB + m], s);
            s = fmaf(v.z, Wm2[(h + 2) * MOLB + m], s);
            s = fmaf(v.w, Wm2[(h + 3) * MOLB + m], s);
        }
        atomicAdd(&mol_fp[(conf / N_CONFS_PER) * MOLB + m], s * boltz[conf]);
    }
}

// ---------------- final readout MLP + sigmoid ----------------
__global__ __launch_bounds__(256) void k_final(
    const float* __restrict__ mol_fp,
    const float* __restrict__ Wr1, const float* __restrict__ br1,
    const float* __restrict__ Wr2, const float* __restrict__ br2,
    float* __restrict__ out)
{
    __shared__ float mf[MOLB];
    __shared__ float t2[D];
    __shared__ float red[4];
    const int mol = blockIdx.x, tid = threadIdx.x;
    mf[tid]       = mol_fp[mol * MOLB + tid];
    mf[tid + 256] = mol_fp[mol * MOLB + tid + 256];
    __syncthreads();
    {
        float s = br1[tid];
        for (int k = 0; k < MOLB; k += 4) {
            const float4 v = *(const float4*)&mf[k];
            s = fmaf(v.x, Wr1[(k + 0) * D + tid], s);
            s = fmaf(v.y, Wr1[(k + 1) * D + tid], s);
            s = fmaf(v.z, Wr1[(k + 2) * D + tid], s);
            s = fmaf(v.w, Wr1[(k + 3) * D + tid], s);
        }
        t2[tid] = sspf(s);
    }
    __syncthreads();
    float p = t2[tid] * Wr2[tid];
#pragma unroll
    for (int o = 32; o > 0; o >>= 1) p += __shfl_down(p, o);
    if ((tid & 63) == 0) red[tid >> 6] = p;
    __syncthreads();
    if (tid == 0) {
        float logit = red[0] + red[1] + red[2] + red[3] + br2[0];
        out[mol] = 1.f / (1.f + expf(-logit));
    }
}

extern "C" void kernel_launch(void* const* d_in, const int* in_sizes, int n_in,
                              void* d_out, int out_size, void* d_ws, size_t ws_size,
                              hipStream_t stream)
{
    const int*   z     = (const int*)d_in[0];
    const float* xyz   = (const float*)d_in[1];
    const int*   nbr   = (const int*)d_in[2];
    const float* boltz = (const float*)d_in[3];
    const float* emb   = (const float*)d_in[4];
    const float* We1   = (const float*)d_in[5];
    const float* be1   = (const float*)d_in[6];
    const float* We2   = (const float*)d_in[7];
    const float* be2   = (const float*)d_in[8];
    const float* Wn    = (const float*)d_in[9];
    const float* bn    = (const float*)d_in[10];
    const float* Wu1   = (const float*)d_in[11];
    const float* bu1   = (const float*)d_in[12];
    const float* Wu2   = (const float*)d_in[13];
    const float* bu2   = (const float*)d_in[14];
    const float* Wm1   = (const float*)d_in[15];
    const float* bm1   = (const float*)d_in[16];
    const float* Wm2   = (const float*)d_in[17];
    const float* bm2   = (const float*)d_in[18];
    const float* Wr1   = (const float*)d_in[19];
    const float* br1   = (const float*)d_in[20];
    const float* Wr2   = (const float*)d_in[21];
    const float* br2   = (const float*)d_in[22];

    char* ws = (char*)d_ws;
    unsigned* cursors        = (unsigned*)ws;                   // 2560 B
    float*    mol_fp         = (float*)(ws + 2560);             // 131072 B -> 133632
    unsigned* esort          = (unsigned*)(ws + 133632);        // 2621440 B -> 2755072
    float*    conf_fp        = (float*)(ws + 2755072);          // 655360 B -> 3410432
    __hip_bfloat16* WT       = (__hip_bfloat16*)(ws + 3410432); // 1572864 B -> 4983296
    __hip_bfloat16* WT2      = (__hip_bfloat16*)(ws + 4983296); // 65536 B -> 5048832
    __hip_bfloat16* We1T     = (__hip_bfloat16*)(ws + 5048832); // 8192 B -> 5057024

    hipMemsetAsync(cursors, 0, 2560 + 131072, stream);          // cursors + mol_fp
    k_prep<<<3072, 256, 0, stream>>>(Wn, Wu1, Wu2, WT);
    k_prep2<<<144, 256, 0, stream>>>(We2, We1, WT2, We1T);
    k_scatter<<<(N_EDGES + 255) / 256, 256, 0, stream>>>(nbr, cursors, esort);
    k_main<<<N_CONFS, TPB, 0, stream>>>(z, xyz, emb, be1, be2, bn,
                                        bu1, bu2, WT, WT2, We1T, cursors, esort, conf_fp);
    k_mol<<<N_CONFS, 512, 0, stream>>>(conf_fp, Wm1, bm1, Wm2, bm2, boltz, mol_fp);
    k_final<<<N_MOLS, 256, 0, stream>>>(mol_fp, Wr1, br1, Wr2, br2, (float*)d_out);
}

// Round 14
// 1091.366 us; speedup vs baseline: 1.1973x; 1.0364x over previous
//
#include <hip/hip_runtime.h>
#include <hip/hip_bf16.h>

#define N_MOLS      64
#define N_CONFS_PER 10
#define A_ATOMS     40
#define N_CONFS     640
#define N_ATOMS     25600
#define N_EDGES     409600
#define D           256
#define NG          32
#define NLAYERS     4
#define MOLB        512
#define H_MOL       384
#define EDGE_CAP    1024
#define EB          32    // edge batch
#define NBMAX       32    // max batches (EDGE_CAP/EB)
#define SHBP        36    // sHb row stride (halfwords)
#define SEFP        260   // sEFs row stride (halfwords)
#define SBH         256   // bf16 tile row stride (halfwords), XOR-swizzled
#define TPB         512   // 8 waves

typedef __attribute__((ext_vector_type(8))) short bshort8;
typedef __attribute__((ext_vector_type(4))) float f32x4;

// swizzled halfword index into a [48][SBH] bf16 tile (conflict-free b128 A-frag reads)
#define SWZ(row, hw) (((row) << 8) + ((hw) ^ (((row) & 7) << 3)))

__device__ __forceinline__ float sspf(float x) {
    return fmaxf(x, 0.f) + log1pf(expf(-fabsf(x))) - 0.69314718055994531f;
}
__device__ __forceinline__ float b2f(short s) {
    union { unsigned u; float f; } u;
    u.u = ((unsigned)(unsigned short)s) << 16;
    return u.f;
}
__device__ __forceinline__ short f2bf(float x) {
    return (short)(unsigned short)((__float_as_uint(x) + 0x8000u) >> 16);
}
__device__ __forceinline__ unsigned pkbf(float lo_e, float hi_e) {
    return __builtin_amdgcn_perm(__float_as_uint(hi_e) + 0x8000u,
                                 __float_as_uint(lo_e) + 0x8000u, 0x07060302u);
}

// ---------------- weight prep: dense W[l][k][n] fp32 -> WT[mat][l][n][k] bf16 ----------------
__global__ __launch_bounds__(256) void k_prep(const float* __restrict__ Wn,
                                              const float* __restrict__ Wu1,
                                              const float* __restrict__ Wu2,
                                              __hip_bfloat16* __restrict__ WT) {
    int idx = blockIdx.x * 256 + threadIdx.x;       // 3*4*256*256
    int k = idx & 255;
    int n = (idx >> 8) & 255;
    int l = (idx >> 16) & 3;
    int mat = idx >> 18;
    const float* src = (mat == 0) ? Wn : (mat == 1) ? Wu1 : Wu2;
    WT[idx] = __float2bfloat16(src[((size_t)l * 256 + k) * 256 + n]);
}

// WT2[l][n][k] bf16 from We2[l][k][n]; We1T[l][t][m] bf16 from We1[l][m][t]
__global__ __launch_bounds__(256) void k_prep2(const float* __restrict__ We2,
                                               const float* __restrict__ We1,
                                               __hip_bfloat16* __restrict__ WT2,
                                               __hip_bfloat16* __restrict__ We1T) {
    int idx = blockIdx.x * 256 + threadIdx.x;       // 32768 + 4096
    if (idx < 32768) {
        int k = idx & 31;
        int n = (idx >> 5) & 255;
        int l = idx >> 13;
        WT2[idx] = __float2bfloat16(We2[((size_t)l * 32 + k) * 256 + n]);
    } else {
        int j = idx - 32768;
        int m = j & 31;
        int t = (j >> 5) & 31;
        int l = j >> 10;
        We1T[j] = __float2bfloat16(We1[((size_t)l * 32 + m) * 32 + t]);
    }
}

// ---------------- edge bucketing by conformer ----------------
__global__ __launch_bounds__(256) void k_scatter(const int* __restrict__ nbr,
                                                 unsigned* __restrict__ cursors,
                                                 unsigned* __restrict__ esort) {
    int e = blockIdx.x * 256 + threadIdx.x;
    if (e >= N_EDGES) return;
    int a0 = nbr[2 * e], a1 = nbr[2 * e + 1];
    int conf = a0 / A_ATOMS;
    int a0l = a0 - conf * A_ATOMS;
    int a1l = a1 - conf * A_ATOMS;
    unsigned r = atomicAdd(&cursors[conf], 1u);
    if (r < EDGE_CAP) esort[conf * EDGE_CAP + r] = (unsigned)((a0l << 6) | a1l);
}

// dense MFMA from bf16 swizzled tile: wave -> 3 m-tiles x n-tiles {2wv, 2wv+1}
__device__ __forceinline__ void mfma_dense8b(const short* __restrict__ src,
                                             const __hip_bfloat16* __restrict__ WT,
                                             f32x4 acc[3][2], int lane, int wv) {
    const int r = lane & 15, g = lane >> 4;
#pragma unroll
    for (int mt = 0; mt < 3; ++mt)
#pragma unroll
        for (int j = 0; j < 2; ++j) acc[mt][j] = (f32x4){0.f, 0.f, 0.f, 0.f};
#pragma unroll 2
    for (int kt = 0; kt < 8; ++kt) {
        const int ko = kt * 32 + g * 8;
        bshort8 a0 = *(const bshort8*)&src[SWZ(0 * 16 + r, ko)];
        bshort8 a1 = *(const bshort8*)&src[SWZ(1 * 16 + r, ko)];
        bshort8 a2 = *(const bshort8*)&src[SWZ(2 * 16 + r, ko)];
#pragma unroll
        for (int j = 0; j < 2; ++j) {
            const int nt = wv * 2 + j;
            bshort8 b = *(const bshort8*)&WT[(nt * 16 + r) * 256 + ko];
            acc[0][j] = __builtin_amdgcn_mfma_f32_16x16x32_bf16(a0, b, acc[0][j], 0, 0, 0);
            acc[1][j] = __builtin_amdgcn_mfma_f32_16x16x32_bf16(a1, b, acc[1][j], 0, 0, 0);
            acc[2][j] = __builtin_amdgcn_mfma_f32_16x16x32_bf16(a2, b, acc[2][j], 0, 0, 0);
        }
    }
}

// writeback: MODE 0: dst16 = bf16(acc+bias) ; 1: dst16 = bf16(ssp(acc+bias))
template <int MODE>
__device__ __forceinline__ void mfma_wb8b(const f32x4 acc[3][2], short* __restrict__ dst16,
                                          const float* __restrict__ bias, int lane, int wv) {
    const int cc = lane & 15, g = lane >> 4;
    const int cr = g * 4;
#pragma unroll
    for (int j = 0; j < 2; ++j) {
        const int col = (wv * 2 + j) * 16 + cc;
        const float bv = bias[col];
#pragma unroll
        for (int mt = 0; mt < 3; ++mt) {
            if (mt == 2 && g >= 2) continue;   // rows 40..47 are padding
#pragma unroll
            for (int reg = 0; reg < 4; ++reg) {
                const int row = mt * 16 + cr + reg;
                float v = acc[mt][j][reg] + bv;
                if (MODE == 1) v = sspf(v);
                dst16[SWZ(row, col)] = f2bf(v);
            }
        }
    }
}

// ---------------- main per-conformer kernel: 512 threads, 8 waves, 2 blocks/CU ----------------
__global__ __launch_bounds__(TPB, 4) void k_main(
    const int* __restrict__ z, const float* __restrict__ xyz,
    const float* __restrict__ emb,
    const float* __restrict__ be1, const float* __restrict__ be2,
    const float* __restrict__ bn,
    const float* __restrict__ bu1, const float* __restrict__ bu2,
    const __hip_bfloat16* __restrict__ WT,
    const __hip_bfloat16* __restrict__ WT2,
    const __hip_bfloat16* __restrict__ We1T,
    const unsigned* __restrict__ cursors, const unsigned* __restrict__ esort,
    float* __restrict__ conf_fp)
{
    __shared__ short sRb[48 * SBH];           // r bf16, swizzled (24.6KB)
    __shared__ short sBb[48 * SBH];           // rn -> agg -> t bf16, swizzled (24.6KB)
    __shared__ __align__(16) char uEFbuf[EB * SEFP * 2];  // 16.6KB: sEFs | setup{xyz,z,deg} | colsum
    __shared__ __align__(16) char sHbBuf[2 * EB * SHBP * 2]; // 4.6KB: sHb | setup sEdge
    __shared__ float sDall[EDGE_CAP];         // scaled distances, zero-padded (4KB)
    __shared__ unsigned short sCsr[2 * EDGE_CAP];          // (src<<10)|edge (4KB)
    __shared__ unsigned short sWin[A_ATOMS * (NBMAX + 1)]; // per-(atom,batch) cursor (2.6KB)
    __shared__ int sPtr[A_ATOMS + 1];

    short* sEFs = (short*)uEFbuf;
    float* colsum = (float*)uEFbuf;
    float (*sXYZ)[3] = (float(*)[3])uEFbuf;       // setup alias
    int* sZ   = (int*)(uEFbuf + 480);             // setup alias
    int* sDeg = (int*)(uEFbuf + 640);             // setup alias
    short (*sHb)[EB * SHBP] = (short(*)[EB * SHBP])sHbBuf;
    unsigned* sEdge = (unsigned*)sHbBuf;          // setup alias (4KB <= 4.6KB)

    const int tid  = threadIdx.x;
    const int lane = tid & 63;
    const int wv   = tid >> 6;        // 0..7
    const int c4   = lane << 2;
    const int conf = blockIdx.x;
    const int fr = lane & 15, fg = lane >> 4, g8 = (lane >> 4) << 3;
    const int mtx = wv & 1;           // X2 m-tile (waves 0..3)
    const int ttx = (wv >> 1) & 1;    // X2 t-tile

    if (tid < A_ATOMS) {
        int ga = conf * A_ATOMS + tid;
        sZ[tid] = z[ga];
        sXYZ[tid][0] = xyz[ga * 3 + 0];
        sXYZ[tid][1] = xyz[ga * 3 + 1];
        sXYZ[tid][2] = xyz[ga * 3 + 2];
        sDeg[tid] = 0;
    }
    for (int i = tid; i < 8 * SBH; i += TPB) {   // zero bf16 pad rows 40..47
        sRb[40 * SBH + i] = 0;
        sBb[40 * SBH + i] = 0;
    }
    __syncthreads();
    float embsum = 0.f;
    {   // embedding init: bf16 r + f32 emb partial (rows q::2, col c)
        const int c = tid & 255, q = tid >> 8;
        for (int aa = q; aa < A_ATOMS; aa += 2) {
            float v = emb[sZ[aa] * D + c];
            embsum += v;
            sRb[SWZ(aa, c)] = f2bf(v);
        }
    }
    int cnt = (int)cursors[conf];
    if (cnt > EDGE_CAP) cnt = EDGE_CAP;
    const unsigned* eptr = esort + conf * EDGE_CAP;
    for (int i = tid; i < cnt; i += TPB) {
        unsigned pe = eptr[i];
        sEdge[i] = pe;
        int a0l = (pe >> 6) & 63, a1l = pe & 63;
        float dx = sXYZ[a0l][0] - sXYZ[a1l][0];
        float dy = sXYZ[a0l][1] - sXYZ[a1l][1];
        float dz = sXYZ[a0l][2] - sXYZ[a1l][2];
        sDall[i] = sqrtf(dx * dx + dy * dy + dz * dz) * (31.0f / 5.0f);
        atomicAdd(&sDeg[a0l], 1);
        atomicAdd(&sDeg[a1l], 1);
    }
    for (int i = cnt + tid; i < EDGE_CAP; i += TPB) sDall[i] = 0.f;
    __syncthreads();
    if (tid == 0) {
        int s = 0;
        for (int a = 0; a < A_ATOMS; ++a) { sPtr[a] = s; s += sDeg[a]; }
        sPtr[A_ATOMS] = s;
    }
    __syncthreads();
    const int NB = (cnt + EB - 1) / EB;
    // ordered CSR fill + per-batch windows (thread a owns its segment)
    if (tid < A_ATOMS) {
        const int ps = sPtr[tid];
        int pos = ps;
        for (int i = 0; i < cnt; ++i) {
            unsigned pe = sEdge[i];
            int a0l = (pe >> 6) & 63, a1l = pe & 63;
            if (a0l == tid) sCsr[pos++] = (unsigned short)((a1l << 10) | i);
            if (a1l == tid) sCsr[pos++] = (unsigned short)((a0l << 10) | i);
        }
        int p = ps;
        for (int b = 0; b <= NB; ++b) {
            const int lim = b * EB;
            while (p < pos && (int)(sCsr[p] & 1023) < lim) ++p;
            sWin[tid * (NBMAX + 1) + b] = (unsigned short)p;
        }
    }

    // f32 per-column delta accumulator (2 regs instead of 24: only column sums are needed)
    float csum[2] = {0.f, 0.f};

    for (int l = 0; l < NLAYERS; ++l) {
        __syncthreads();
        // ---- M1: sBb = bf16(r @ Wn + bn)
        {
            f32x4 acc[3][2];
            mfma_dense8b(sRb, WT + ((size_t)(0 * 4 + l) << 16), acc, lane, wv);
            mfma_wb8b<0>(acc, sBb, bn + l * D, lane, wv);
        }
        __syncthreads();
        // ---- edge phase: balanced 2-barrier pipeline, batches of 32
        float4 agg[5];
#pragma unroll
        for (int k = 0; k < 5; ++k) agg[k] = make_float4(0.f, 0.f, 0.f, 0.f);
        {
            const bshort8 bf0 = *(const bshort8*)&WT2[(size_t)l * 8192 + ((2 * wv + 0) * 16 + fr) * 32 + g8];
            const bshort8 bf1 = *(const bshort8*)&WT2[(size_t)l * 8192 + ((2 * wv + 1) * 16 + fr) * 32 + g8];
            const float bb0 = be2[l * D + (2 * wv + 0) * 16 + fr];
            const float bb1 = be2[l * D + (2 * wv + 1) * 16 + fr];
            const bshort8 bfX = *(const bshort8*)&We1T[(size_t)l * 1024 + (ttx * 16 + fr) * 32 + g8];
            const float bbX = be1[l * NG + ttx * 16 + fr];

            // prologue: X2(0) -> sHb[0] (waves 0..3)
            if (wv < 4 && NB > 0) {
                const float dd = sDall[mtx * 16 + fr];
                union { bshort8 v; unsigned u[4]; } ua;
#pragma unroll
                for (int j = 0; j < 4; ++j) {
                    const float u0 = dd - (float)(g8 + 2 * j + 0);
                    const float u1 = dd - (float)(g8 + 2 * j + 1);
                    ua.u[j] = pkbf(expf(-0.5f * u0 * u0), expf(-0.5f * u1 * u1));
                }
                f32x4 c = (f32x4){0.f, 0.f, 0.f, 0.f};
                c = __builtin_amdgcn_mfma_f32_16x16x32_bf16(ua.v, bfX, c, 0, 0, 0);
#pragma unroll
                for (int reg = 0; reg < 4; ++reg) {
                    const int erow = mtx * 16 + fg * 4 + reg;
                    sHb[0][erow * SHBP + ttx * 16 + fr] = f2bf(sspf(c[reg] + bbX));
                }
            }
            __syncthreads();
            for (int b = 0; b < NB; ++b) {
                const int base = b * EB;
                // ---- phase1: P4(b) all waves; X2(b+1) waves 0..3
                {
                    const short* __restrict__ hb = sHb[b & 1];
#pragma unroll
                    for (int mt = 0; mt < 2; ++mt) {
                        union { bshort8 v; short4 s[2]; } af;
                        af.s[0] = *(const short4*)&hb[(mt * 16 + fr) * SHBP + g8];
                        af.s[1] = *(const short4*)&hb[(mt * 16 + fr) * SHBP + g8 + 4];
                        f32x4 c0 = (f32x4){0.f, 0.f, 0.f, 0.f};
                        c0 = __builtin_amdgcn_mfma_f32_16x16x32_bf16(af.v, bf0, c0, 0, 0, 0);
                        f32x4 c1 = (f32x4){0.f, 0.f, 0.f, 0.f};
                        c1 = __builtin_amdgcn_mfma_f32_16x16x32_bf16(af.v, bf1, c1, 0, 0, 0);
#pragma unroll
                        for (int reg = 0; reg < 4; ++reg) {
                            const int erow = mt * 16 + fg * 4 + reg;
                            sEFs[erow * SEFP + (2 * wv + 0) * 16 + fr] = f2bf(c0[reg] + bb0);
                            sEFs[erow * SEFP + (2 * wv + 1) * 16 + fr] = f2bf(c1[reg] + bb1);
                        }
                    }
                }
                if (wv < 4 && b + 1 < NB) {
                    short* __restrict__ hb = sHb[(b + 1) & 1];
                    const float dd = sDall[(b + 1) * EB + mtx * 16 + fr];
                    union { bshort8 v; unsigned u[4]; } ua;
#pragma unroll
                    for (int j = 0; j < 4; ++j) {
                        const float u0 = dd - (float)(g8 + 2 * j + 0);
                        const float u1 = dd - (float)(g8 + 2 * j + 1);
                        ua.u[j] = pkbf(expf(-0.5f * u0 * u0), expf(-0.5f * u1 * u1));
                    }
                    f32x4 c = (f32x4){0.f, 0.f, 0.f, 0.f};
                    c = __builtin_amdgcn_mfma_f32_16x16x32_bf16(ua.v, bfX, c, 0, 0, 0);
#pragma unroll
                    for (int reg = 0; reg < 4; ++reg) {
                        const int erow = mtx * 16 + fg * 4 + reg;
                        hb[erow * SHBP + ttx * 16 + fr] = f2bf(sspf(c[reg] + bbX));
                    }
                }
                __syncthreads();
                // ---- phase2: P5 counted gathers (wave owns rows 5wv..5wv+4)
#pragma unroll
                for (int k = 0; k < 5; ++k) {
                    const int row = wv * 5 + k;
                    const int st = (int)sWin[row * (NBMAX + 1) + b];
                    const int en = (int)sWin[row * (NBMAX + 1) + b + 1];
                    for (int i = st; i < en; ++i) {
                        const int ent = (int)sCsr[i];
                        const int e = ent & 1023, src = ent >> 10;
                        const short4 f4 = *(const short4*)&sEFs[(e - base) * SEFP + c4];
                        const short4 r4 = *(const short4*)&sBb[SWZ(src, c4)];
                        agg[k].x = fmaf(b2f(f4.x), b2f(r4.x), agg[k].x);
                        agg[k].y = fmaf(b2f(f4.y), b2f(r4.y), agg[k].y);
                        agg[k].z = fmaf(b2f(f4.z), b2f(r4.z), agg[k].z);
                        agg[k].w = fmaf(b2f(f4.w), b2f(r4.w), agg[k].w);
                    }
                }
                __syncthreads();
            }
        }
        // agg -> sBb (rn dead)
#pragma unroll
        for (int k = 0; k < 5; ++k) {
            uint2 p;
            p.x = pkbf(agg[k].x, agg[k].y);
            p.y = pkbf(agg[k].z, agg[k].w);
            *(uint2*)&sBb[SWZ(wv * 5 + k, c4)] = p;
        }
        __syncthreads();
        // ---- M2: sBb = bf16(ssp(agg @ Wu1 + bu1))  (in-place: sync between acc and wb)
        {
            f32x4 acc[3][2];
            mfma_dense8b(sBb, WT + ((size_t)(1 * 4 + l) << 16), acc, lane, wv);
            __syncthreads();
            mfma_wb8b<1>(acc, sBb, bu1 + l * D, lane, wv);
        }
        __syncthreads();
        // ---- M3: delta = t @ Wu2 + bu2; csum[j] += col-sum of delta (f32); r_bf16 += delta
        {
            f32x4 acc[3][2];
            mfma_dense8b(sBb, WT + ((size_t)(2 * 4 + l) << 16), acc, lane, wv);
            const int cc = lane & 15, g = lane >> 4, cr = g * 4;
#pragma unroll
            for (int j = 0; j < 2; ++j) {
                const int col = (wv * 2 + j) * 16 + cc;
                const float bv = bu2[l * D + col];
#pragma unroll
                for (int mt = 0; mt < 3; ++mt) {
                    if (mt == 2 && g >= 2) continue;
#pragma unroll
                    for (int reg = 0; reg < 4; ++reg) {
                        const int row = mt * 16 + cr + reg;
                        float v = acc[mt][j][reg] + bv;
                        csum[j] += v;
                        const int idx = SWZ(row, col);
                        sRb[idx] = f2bf(b2f(sRb[idx]) + v);
                    }
                }
            }
        }
    }
    // ---- output: colsum = sum over atoms of (emb + sum of deltas), all f32
    __syncthreads();
    if (tid < D) colsum[tid] = 0.f;
    __syncthreads();
    {
        const int cc = lane & 15;
#pragma unroll
        for (int j = 0; j < 2; ++j)
            atomicAdd(&colsum[(wv * 2 + j) * 16 + cc], csum[j]);
        atomicAdd(&colsum[tid & 255], embsum);
    }
    __syncthreads();
    if (tid < D) conf_fp[conf * D + tid] = colsum[tid];
}

// ---------------- per-conformer molecular MLP + Boltzmann-weighted reduce ----------------
__global__ __launch_bounds__(512) void k_mol(
    const float* __restrict__ conf_fp,
    const float* __restrict__ Wm1, const float* __restrict__ bm1,
    const float* __restrict__ Wm2, const float* __restrict__ bm2,
    const float* __restrict__ boltz, float* __restrict__ mol_fp)
{
    __shared__ float cf[D];
    __shared__ float t[H_MOL];
    const int conf = blockIdx.x;
    const int tid = threadIdx.x;
    if (tid < D) cf[tid] = conf_fp[conf * D + tid];
    __syncthreads();
    if (tid < H_MOL) {
        float s = bm1[tid];
        for (int k = 0; k < D; k += 4) {
            const float4 v = *(const float4*)&cf[k];
            s = fmaf(v.x, Wm1[(k + 0) * H_MOL + tid], s);
            s = fmaf(v.y, Wm1[(k + 1) * H_MOL + tid], s);
            s = fmaf(v.z, Wm1[(k + 2) * H_MOL + tid], s);
            s = fmaf(v.w, Wm1[(k + 3) * H_MOL + tid], s);
        }
        t[tid] = sspf(s);
    }
    __syncthreads();
    {
        const int m = tid;
        float s = bm2[m];
        for (int h = 0; h < H_MOL; h += 4) {
            const float4 v = *(const float4*)&t[h];
            s = fmaf(v.x, Wm2[(h + 0) * MOLB + m], s);
            s = fmaf(v.y, Wm2[(h + 1) * MOLB + m], s);
            s = fmaf(v.z, Wm2[(h + 2) * MOLB + m], s);
            s = fmaf(v.w, Wm2[(h + 3) * MOLB + m], s);
        }
        atomicAdd(&mol_fp[(conf / N_CONFS_PER) * MOLB + m], s * boltz[conf]);
    }
}

// ---------------- final readout MLP + sigmoid ----------------
__global__ __launch_bounds__(256) void k_final(
    const float* __restrict__ mol_fp,
    const float* __restrict__ Wr1, const float* __restrict__ br1,
    const float* __restrict__ Wr2, const float* __restrict__ br2,
    float* __restrict__ out)
{
    __shared__ float mf[MOLB];
    __shared__ float t2[D];
    __shared__ float red[4];
    const int mol = blockIdx.x, tid = threadIdx.x;
    mf[tid]       = mol_fp[mol * MOLB + tid];
    mf[tid + 256] = mol_fp[mol * MOLB + tid + 256];
    __syncthreads();
    {
        float s = br1[tid];
        for (int k = 0; k < MOLB; k += 4) {
            const float4 v = *(const float4*)&mf[k];
            s = fmaf(v.x, Wr1[(k + 0) * D + tid], s);
            s = fmaf(v.y, Wr1[(k + 1) * D + tid], s);
            s = fmaf(v.z, Wr1[(k + 2) * D + tid], s);
            s = fmaf(v.w, Wr1[(k + 3) * D + tid], s);
        }
        t2[tid] = sspf(s);
    }
    __syncthreads();
    float p = t2[tid] * Wr2[tid];
#pragma unroll
    for (int o = 32; o > 0; o >>= 1) p += __shfl_down(p, o);
    if ((tid & 63) == 0) red[tid >> 6] = p;
    __syncthreads();
    if (tid == 0) {
        float logit = red[0] + red[1] + red[2] + red[3] + br2[0];
        out[mol] = 1.f / (1.f + expf(-logit));
    }
}

extern "C" void kernel_launch(void* const* d_in, const int* in_sizes, int n_in,
                              void* d_out, int out_size, void* d_ws, size_t ws_size,
                              hipStream_t stream)
{
    const int*   z     = (const int*)d_in[0];
    const float* xyz   = (const float*)d_in[1];
    const int*   nbr   = (const int*)d_in[2];
    const float* boltz = (const float*)d_in[3];
    const float* emb   = (const float*)d_in[4];
    const float* We1   = (const float*)d_in[5];
    const float* be1   = (const float*)d_in[6];
    const float* We2   = (const float*)d_in[7];
    const float* be2   = (const float*)d_in[8];
    const float* Wn    = (const float*)d_in[9];
    const float* bn    = (const float*)d_in[10];
    const float* Wu1   = (const float*)d_in[11];
    const float* bu1   = (const float*)d_in[12];
    const float* Wu2   = (const float*)d_in[13];
    const float* bu2   = (const float*)d_in[14];
    const float* Wm1   = (const float*)d_in[15];
    const float* bm1   = (const float*)d_in[16];
    const float* Wm2   = (const float*)d_in[17];
    const float* bm2   = (const float*)d_in[18];
    const float* Wr1   = (const float*)d_in[19];
    const float* br1   = (const float*)d_in[20];
    const float* Wr2   = (const float*)d_in[21];
    const float* br2   = (const float*)d_in[22];

    char* ws = (char*)d_ws;
    unsigned* cursors        = (unsigned*)ws;                   // 2560 B
    float*    mol_fp         = (float*)(ws + 2560);             // 131072 B -> 133632
    unsigned* esort          = (unsigned*)(ws + 133632);        // 2621440 B -> 2755072
    float*    conf_fp        = (float*)(ws + 2755072);          // 655360 B -> 3410432
    __hip_bfloat16* WT       = (__hip_bfloat16*)(ws + 3410432); // 1572864 B -> 4983296
    __hip_bfloat16* WT2      = (__hip_bfloat16*)(ws + 4983296); // 65536 B -> 5048832
    __hip_bfloat16* We1T     = (__hip_bfloat16*)(ws + 5048832); // 8192 B -> 5057024

    hipMemsetAsync(cursors, 0, 2560 + 131072, stream);          // cursors + mol_fp
    k_prep<<<3072, 256, 0, stream>>>(Wn, Wu1, Wu2, WT);
    k_prep2<<<144, 256, 0, stream>>>(We2, We1, WT2, We1T);
    k_scatter<<<(N_EDGES + 255) / 256, 256, 0, stream>>>(nbr, cursors, esort);
    k_main<<<N_CONFS, TPB, 0, stream>>>(z, xyz, emb, be1, be2, bn,
                                        bu1, bu2, WT, WT2, We1T, cursors, esort, conf_fp);
    k_mol<<<N_CONFS, 512, 0, stream>>>(conf_fp, Wm1, bm1, Wm2, bm2, boltz, mol_fp);
    k_final<<<N_MOLS, 256, 0, stream>>>(mol_fp, Wr1, br1, Wr2, br2, (float*)d_out);
}

// Round 15
// 855.764 us; speedup vs baseline: 1.5270x; 1.2753x over previous
//
#include <hip/hip_runtime.h>
#include <hip/hip_bf16.h>

#define N_MOLS      64
#define N_CONFS_PER 10
#define A_ATOMS     40
#define N_CONFS     640
#define N_ATOMS     25600
#define N_EDGES     409600
#define D           256
#define NG          32
#define NLAYERS     4
#define MOLB        512
#define H_MOL       384
#define EDGE_CAP    1024
#define EB          32    // edge batch
#define NBMAX       32    // max batches (EDGE_CAP/EB)
#define SHBP        36    // sHb row stride (halfwords)
#define SEFP        260   // sEFs row stride (halfwords)
#define SBH         256   // bf16 tile row stride (halfwords), XOR-swizzled
#define TPB         512   // 8 waves

typedef __attribute__((ext_vector_type(8))) short bshort8;
typedef __attribute__((ext_vector_type(4))) float f32x4;

// swizzled halfword index into a [48][SBH] bf16 tile (conflict-free b128 A-frag reads)
#define SWZ(row, hw) (((row) << 8) + ((hw) ^ (((row) & 7) << 3)))

// fast ssp via HW v_exp_f32/v_log_f32 (~6 inst); bf16 downstream rounding swamps 1-2ulp err
__device__ __forceinline__ float sspf(float x) {
    return fmaxf(x, 0.f) + __logf(1.f + __expf(-fabsf(x))) - 0.69314718055994531f;
}
__device__ __forceinline__ float b2f(short s) {
    union { unsigned u; float f; } u;
    u.u = ((unsigned)(unsigned short)s) << 16;
    return u.f;
}
__device__ __forceinline__ short f2bf(float x) {
    return (short)(unsigned short)((__float_as_uint(x) + 0x8000u) >> 16);
}
__device__ __forceinline__ unsigned pkbf(float lo_e, float hi_e) {
    return __builtin_amdgcn_perm(__float_as_uint(hi_e) + 0x8000u,
                                 __float_as_uint(lo_e) + 0x8000u, 0x07060302u);
}

// ---------------- weight prep: dense W[l][k][n] fp32 -> WT[mat][l][n][k] bf16 ----------------
__global__ __launch_bounds__(256) void k_prep(const float* __restrict__ Wn,
                                              const float* __restrict__ Wu1,
                                              const float* __restrict__ Wu2,
                                              __hip_bfloat16* __restrict__ WT) {
    int idx = blockIdx.x * 256 + threadIdx.x;       // 3*4*256*256
    int k = idx & 255;
    int n = (idx >> 8) & 255;
    int l = (idx >> 16) & 3;
    int mat = idx >> 18;
    const float* src = (mat == 0) ? Wn : (mat == 1) ? Wu1 : Wu2;
    WT[idx] = __float2bfloat16(src[((size_t)l * 256 + k) * 256 + n]);
}

// WT2[l][n][k] bf16 from We2[l][k][n]; We1T[l][t][m] bf16 from We1[l][m][t]
__global__ __launch_bounds__(256) void k_prep2(const float* __restrict__ We2,
                                               const float* __restrict__ We1,
                                               __hip_bfloat16* __restrict__ WT2,
                                               __hip_bfloat16* __restrict__ We1T) {
    int idx = blockIdx.x * 256 + threadIdx.x;       // 32768 + 4096
    if (idx < 32768) {
        int k = idx & 31;
        int n = (idx >> 5) & 255;
        int l = idx >> 13;
        WT2[idx] = __float2bfloat16(We2[((size_t)l * 32 + k) * 256 + n]);
    } else {
        int j = idx - 32768;
        int m = j & 31;
        int t = (j >> 5) & 31;
        int l = j >> 10;
        We1T[j] = __float2bfloat16(We1[((size_t)l * 32 + m) * 32 + t]);
    }
}

// ---------------- edge bucketing by conformer ----------------
__global__ __launch_bounds__(256) void k_scatter(const int* __restrict__ nbr,
                                                 unsigned* __restrict__ cursors,
                                                 unsigned* __restrict__ esort) {
    int e = blockIdx.x * 256 + threadIdx.x;
    if (e >= N_EDGES) return;
    int a0 = nbr[2 * e], a1 = nbr[2 * e + 1];
    int conf = a0 / A_ATOMS;
    int a0l = a0 - conf * A_ATOMS;
    int a1l = a1 - conf * A_ATOMS;
    unsigned r = atomicAdd(&cursors[conf], 1u);
    if (r < EDGE_CAP) esort[conf * EDGE_CAP + r] = (unsigned)((a0l << 6) | a1l);
}

// dense MFMA from bf16 swizzled tile: wave -> 3 m-tiles x n-tiles {2wv, 2wv+1}
__device__ __forceinline__ void mfma_dense8b(const short* __restrict__ src,
                                             const __hip_bfloat16* __restrict__ WT,
                                             f32x4 acc[3][2], int lane, int wv) {
    const int r = lane & 15, g = lane >> 4;
#pragma unroll
    for (int mt = 0; mt < 3; ++mt)
#pragma unroll
        for (int j = 0; j < 2; ++j) acc[mt][j] = (f32x4){0.f, 0.f, 0.f, 0.f};
#pragma unroll 2
    for (int kt = 0; kt < 8; ++kt) {
        const int ko = kt * 32 + g * 8;
        bshort8 a0 = *(const bshort8*)&src[SWZ(0 * 16 + r, ko)];
        bshort8 a1 = *(const bshort8*)&src[SWZ(1 * 16 + r, ko)];
        bshort8 a2 = *(const bshort8*)&src[SWZ(2 * 16 + r, ko)];
#pragma unroll
        for (int j = 0; j < 2; ++j) {
            const int nt = wv * 2 + j;
            bshort8 b = *(const bshort8*)&WT[(nt * 16 + r) * 256 + ko];
            acc[0][j] = __builtin_amdgcn_mfma_f32_16x16x32_bf16(a0, b, acc[0][j], 0, 0, 0);
            acc[1][j] = __builtin_amdgcn_mfma_f32_16x16x32_bf16(a1, b, acc[1][j], 0, 0, 0);
            acc[2][j] = __builtin_amdgcn_mfma_f32_16x16x32_bf16(a2, b, acc[2][j], 0, 0, 0);
        }
    }
}

// writeback: MODE 0: dst16 = bf16(acc+bias) ; 1: dst16 = bf16(ssp(acc+bias))
template <int MODE>
__device__ __forceinline__ void mfma_wb8b(const f32x4 acc[3][2], short* __restrict__ dst16,
                                          const float* __restrict__ bias, int lane, int wv) {
    const int cc = lane & 15, g = lane >> 4;
    const int cr = g * 4;
#pragma unroll
    for (int j = 0; j < 2; ++j) {
        const int col = (wv * 2 + j) * 16 + cc;
        const float bv = bias[col];
#pragma unroll
        for (int mt = 0; mt < 3; ++mt) {
            if (mt == 2 && g >= 2) continue;   // rows 40..47 are padding
#pragma unroll
            for (int reg = 0; reg < 4; ++reg) {
                const int row = mt * 16 + cr + reg;
                float v = acc[mt][j][reg] + bv;
                if (MODE == 1) v = sspf(v);
                dst16[SWZ(row, col)] = f2bf(v);
            }
        }
    }
}

// ---------------- main per-conformer kernel: 512 threads, 8 waves, 2 blocks/CU ----------------
__global__ __launch_bounds__(TPB, 4) void k_main(
    const int* __restrict__ z, const float* __restrict__ xyz,
    const float* __restrict__ emb,
    const float* __restrict__ be1, const float* __restrict__ be2,
    const float* __restrict__ bn,
    const float* __restrict__ bu1, const float* __restrict__ bu2,
    const __hip_bfloat16* __restrict__ WT,
    const __hip_bfloat16* __restrict__ WT2,
    const __hip_bfloat16* __restrict__ We1T,
    const unsigned* __restrict__ cursors, const unsigned* __restrict__ esort,
    float* __restrict__ conf_fp)
{
    __shared__ short sRb[48 * SBH];           // r bf16, swizzled (24.6KB)
    __shared__ short sBb[48 * SBH];           // rn -> agg -> t bf16, swizzled (24.6KB)
    __shared__ __align__(16) char uEFbuf[EB * SEFP * 2];  // 16.6KB: sEFs | setup{xyz,z,deg} | colsum
    __shared__ __align__(16) char sHbBuf[2 * EB * SHBP * 2]; // 4.6KB: sHb | setup sEdge
    __shared__ float sDall[EDGE_CAP];         // scaled distances, zero-padded (4KB)
    __shared__ unsigned short sCsr[2 * EDGE_CAP];          // (src<<10)|edge (4KB)
    __shared__ unsigned short sWin[A_ATOMS * (NBMAX + 1)]; // per-(atom,batch) cursor (2.6KB)
    __shared__ int sPtr[A_ATOMS + 1];

    short* sEFs = (short*)uEFbuf;
    float* colsum = (float*)uEFbuf;
    float (*sXYZ)[3] = (float(*)[3])uEFbuf;       // setup alias
    int* sZ   = (int*)(uEFbuf + 480);             // setup alias
    int* sDeg = (int*)(uEFbuf + 640);             // setup alias
    short (*sHb)[EB * SHBP] = (short(*)[EB * SHBP])sHbBuf;
    unsigned* sEdge = (unsigned*)sHbBuf;          // setup alias (4KB <= 4.6KB)

    const int tid  = threadIdx.x;
    const int lane = tid & 63;
    const int wv   = tid >> 6;        // 0..7
    const int c4   = lane << 2;
    const int conf = blockIdx.x;
    const int fr = lane & 15, fg = lane >> 4, g8 = (lane >> 4) << 3;
    const int mtx = wv & 1;           // X2 m-tile (waves 0..3)
    const int ttx = (wv >> 1) & 1;    // X2 t-tile

    if (tid < A_ATOMS) {
        int ga = conf * A_ATOMS + tid;
        sZ[tid] = z[ga];
        sXYZ[tid][0] = xyz[ga * 3 + 0];
        sXYZ[tid][1] = xyz[ga * 3 + 1];
        sXYZ[tid][2] = xyz[ga * 3 + 2];
        sDeg[tid] = 0;
    }
    for (int i = tid; i < 8 * SBH; i += TPB) {   // zero bf16 pad rows 40..47
        sRb[40 * SBH + i] = 0;
        sBb[40 * SBH + i] = 0;
    }
    __syncthreads();
    float embsum = 0.f;
    {   // embedding init: bf16 r + f32 emb partial (rows q::2, col c)
        const int c = tid & 255, q = tid >> 8;
        for (int aa = q; aa < A_ATOMS; aa += 2) {
            float v = emb[sZ[aa] * D + c];
            embsum += v;
            sRb[SWZ(aa, c)] = f2bf(v);
        }
    }
    int cnt = (int)cursors[conf];
    if (cnt > EDGE_CAP) cnt = EDGE_CAP;
    const unsigned* eptr = esort + conf * EDGE_CAP;
    for (int i = tid; i < cnt; i += TPB) {
        unsigned pe = eptr[i];
        sEdge[i] = pe;
        int a0l = (pe >> 6) & 63, a1l = pe & 63;
        float dx = sXYZ[a0l][0] - sXYZ[a1l][0];
        float dy = sXYZ[a0l][1] - sXYZ[a1l][1];
        float dz = sXYZ[a0l][2] - sXYZ[a1l][2];
        sDall[i] = sqrtf(dx * dx + dy * dy + dz * dz) * (31.0f / 5.0f);
        atomicAdd(&sDeg[a0l], 1);
        atomicAdd(&sDeg[a1l], 1);
    }
    for (int i = cnt + tid; i < EDGE_CAP; i += TPB) sDall[i] = 0.f;
    __syncthreads();
    if (tid == 0) {
        int s = 0;
        for (int a = 0; a < A_ATOMS; ++a) { sPtr[a] = s; s += sDeg[a]; }
        sPtr[A_ATOMS] = s;
    }
    __syncthreads();
    const int NB = (cnt + EB - 1) / EB;
    // ordered CSR fill + per-batch windows (thread a owns its segment)
    if (tid < A_ATOMS) {
        const int ps = sPtr[tid];
        int pos = ps;
        for (int i = 0; i < cnt; ++i) {
            unsigned pe = sEdge[i];
            int a0l = (pe >> 6) & 63, a1l = pe & 63;
            if (a0l == tid) sCsr[pos++] = (unsigned short)((a1l << 10) | i);
            if (a1l == tid) sCsr[pos++] = (unsigned short)((a0l << 10) | i);
        }
        int p = ps;
        for (int b = 0; b <= NB; ++b) {
            const int lim = b * EB;
            while (p < pos && (int)(sCsr[p] & 1023) < lim) ++p;
            sWin[tid * (NBMAX + 1) + b] = (unsigned short)p;
        }
    }

    // f32 per-column delta accumulator (2 regs: only column sums are needed)
    float csum[2] = {0.f, 0.f};

    for (int l = 0; l < NLAYERS; ++l) {
        __syncthreads();
        // ---- M1: sBb = bf16(r @ Wn + bn)
        {
            f32x4 acc[3][2];
            mfma_dense8b(sRb, WT + ((size_t)(0 * 4 + l) << 16), acc, lane, wv);
            mfma_wb8b<0>(acc, sBb, bn + l * D, lane, wv);
        }
        __syncthreads();
        // ---- edge phase: balanced 2-barrier pipeline, batches of 32
        float4 agg[5];
#pragma unroll
        for (int k = 0; k < 5; ++k) agg[k] = make_float4(0.f, 0.f, 0.f, 0.f);
        {
            const bshort8 bf0 = *(const bshort8*)&WT2[(size_t)l * 8192 + ((2 * wv + 0) * 16 + fr) * 32 + g8];
            const bshort8 bf1 = *(const bshort8*)&WT2[(size_t)l * 8192 + ((2 * wv + 1) * 16 + fr) * 32 + g8];
            const float bb0 = be2[l * D + (2 * wv + 0) * 16 + fr];
            const float bb1 = be2[l * D + (2 * wv + 1) * 16 + fr];
            const bshort8 bfX = *(const bshort8*)&We1T[(size_t)l * 1024 + (ttx * 16 + fr) * 32 + g8];
            const float bbX = be1[l * NG + ttx * 16 + fr];

            // prologue: X2(0) -> sHb[0] (waves 0..3)
            if (wv < 4 && NB > 0) {
                const float dd = sDall[mtx * 16 + fr];
                union { bshort8 v; unsigned u[4]; } ua;
#pragma unroll
                for (int j = 0; j < 4; ++j) {
                    const float u0 = dd - (float)(g8 + 2 * j + 0);
                    const float u1 = dd - (float)(g8 + 2 * j + 1);
                    ua.u[j] = pkbf(__expf(-0.5f * u0 * u0), __expf(-0.5f * u1 * u1));
                }
                f32x4 c = (f32x4){0.f, 0.f, 0.f, 0.f};
                c = __builtin_amdgcn_mfma_f32_16x16x32_bf16(ua.v, bfX, c, 0, 0, 0);
#pragma unroll
                for (int reg = 0; reg < 4; ++reg) {
                    const int erow = mtx * 16 + fg * 4 + reg;
                    sHb[0][erow * SHBP + ttx * 16 + fr] = f2bf(sspf(c[reg] + bbX));
                }
            }
            __syncthreads();
            for (int b = 0; b < NB; ++b) {
                const int base = b * EB;
                // ---- phase1: P4(b) all waves; X2(b+1) waves 0..3
                {
                    const short* __restrict__ hb = sHb[b & 1];
#pragma unroll
                    for (int mt = 0; mt < 2; ++mt) {
                        union { bshort8 v; short4 s[2]; } af;
                        af.s[0] = *(const short4*)&hb[(mt * 16 + fr) * SHBP + g8];
                        af.s[1] = *(const short4*)&hb[(mt * 16 + fr) * SHBP + g8 + 4];
                        f32x4 c0 = (f32x4){0.f, 0.f, 0.f, 0.f};
                        c0 = __builtin_amdgcn_mfma_f32_16x16x32_bf16(af.v, bf0, c0, 0, 0, 0);
                        f32x4 c1 = (f32x4){0.f, 0.f, 0.f, 0.f};
                        c1 = __builtin_amdgcn_mfma_f32_16x16x32_bf16(af.v, bf1, c1, 0, 0, 0);
#pragma unroll
                        for (int reg = 0; reg < 4; ++reg) {
                            const int erow = mt * 16 + fg * 4 + reg;
                            sEFs[erow * SEFP + (2 * wv + 0) * 16 + fr] = f2bf(c0[reg] + bb0);
                            sEFs[erow * SEFP + (2 * wv + 1) * 16 + fr] = f2bf(c1[reg] + bb1);
                        }
                    }
                }
                if (wv < 4 && b + 1 < NB) {
                    short* __restrict__ hb = sHb[(b + 1) & 1];
                    const float dd = sDall[(b + 1) * EB + mtx * 16 + fr];
                    union { bshort8 v; unsigned u[4]; } ua;
#pragma unroll
                    for (int j = 0; j < 4; ++j) {
                        const float u0 = dd - (float)(g8 + 2 * j + 0);
                        const float u1 = dd - (float)(g8 + 2 * j + 1);
                        ua.u[j] = pkbf(__expf(-0.5f * u0 * u0), __expf(-0.5f * u1 * u1));
                    }
                    f32x4 c = (f32x4){0.f, 0.f, 0.f, 0.f};
                    c = __builtin_amdgcn_mfma_f32_16x16x32_bf16(ua.v, bfX, c, 0, 0, 0);
#pragma unroll
                    for (int reg = 0; reg < 4; ++reg) {
                        const int erow = mtx * 16 + fg * 4 + reg;
                        hb[erow * SHBP + ttx * 16 + fr] = f2bf(sspf(c[reg] + bbX));
                    }
                }
                __syncthreads();
                // ---- phase2: P5 counted gathers (wave owns rows 5wv..5wv+4)
#pragma unroll
                for (int k = 0; k < 5; ++k) {
                    const int row = wv * 5 + k;
                    const int st = (int)sWin[row * (NBMAX + 1) + b];
                    const int en = (int)sWin[row * (NBMAX + 1) + b + 1];
                    for (int i = st; i < en; ++i) {
                        const int ent = (int)sCsr[i];
                        const int e = ent & 1023, src = ent >> 10;
                        const short4 f4 = *(const short4*)&sEFs[(e - base) * SEFP + c4];
                        const short4 r4 = *(const short4*)&sBb[SWZ(src, c4)];
                        agg[k].x = fmaf(b2f(f4.x), b2f(r4.x), agg[k].x);
                        agg[k].y = fmaf(b2f(f4.y), b2f(r4.y), agg[k].y);
                        agg[k].z = fmaf(b2f(f4.z), b2f(r4.z), agg[k].z);
                        agg[k].w = fmaf(b2f(f4.w), b2f(r4.w), agg[k].w);
                    }
                }
                __syncthreads();
            }
        }
        // agg -> sBb (rn dead)
#pragma unroll
        for (int k = 0; k < 5; ++k) {
            uint2 p;
            p.x = pkbf(agg[k].x, agg[k].y);
            p.y = pkbf(agg[k].z, agg[k].w);
            *(uint2*)&sBb[SWZ(wv * 5 + k, c4)] = p;
        }
        __syncthreads();
        // ---- M2: sBb = bf16(ssp(agg @ Wu1 + bu1))  (in-place: sync between acc and wb)
        {
            f32x4 acc[3][2];
            mfma_dense8b(sBb, WT + ((size_t)(1 * 4 + l) << 16), acc, lane, wv);
            __syncthreads();
            mfma_wb8b<1>(acc, sBb, bu1 + l * D, lane, wv);
        }
        __syncthreads();
        // ---- M3: delta = t @ Wu2 + bu2; csum[j] += col-sum of delta (f32); r_bf16 += delta
        {
            f32x4 acc[3][2];
            mfma_dense8b(sBb, WT + ((size_t)(2 * 4 + l) << 16), acc, lane, wv);
            const int cc = lane & 15, g = lane >> 4, cr = g * 4;
#pragma unroll
            for (int j = 0; j < 2; ++j) {
                const int col = (wv * 2 + j) * 16 + cc;
                const float bv = bu2[l * D + col];
#pragma unroll
                for (int mt = 0; mt < 3; ++mt) {
                    if (mt == 2 && g >= 2) continue;
#pragma unroll
                    for (int reg = 0; reg < 4; ++reg) {
                        const int row = mt * 16 + cr + reg;
                        float v = acc[mt][j][reg] + bv;
                        csum[j] += v;
                        const int idx = SWZ(row, col);
                        sRb[idx] = f2bf(b2f(sRb[idx]) + v);
                    }
                }
            }
        }
    }
    // ---- output: colsum = sum over atoms of (emb + sum of deltas), all f32
    __syncthreads();
    if (tid < D) colsum[tid] = 0.f;
    __syncthreads();
    {
        const int cc = lane & 15;
#pragma unroll
        for (int j = 0; j < 2; ++j)
            atomicAdd(&colsum[(wv * 2 + j) * 16 + cc], csum[j]);
        atomicAdd(&colsum[tid & 255], embsum);
    }
    __syncthreads();
    if (tid < D) conf_fp[conf * D + tid] = colsum[tid];
}

// ---------------- per-conformer molecular MLP + Boltzmann-weighted reduce ----------------
__global__ __launch_bounds__(512) void k_mol(
    const float* __restrict__ conf_fp,
    const float* __restrict__ Wm1, const float* __restrict__ bm1,
    const float* __restrict__ Wm2, const float* __restrict__ bm2,
    const float* __restrict__ boltz, float* __restrict__ mol_fp)
{
    __shared__ float cf[D];
    __shared__ float t[H_MOL];
    const int conf = blockIdx.x;
    const int tid = threadIdx.x;
    if (tid < D) cf[tid] = conf_fp[conf * D + tid];
    __syncthreads();
    if (tid < H_MOL) {
        float s = bm1[tid];
        for (int k = 0; k < D; k += 4) {
            const float4 v = *(const float4*)&cf[k];
            s = fmaf(v.x, Wm1[(k + 0) * H_MOL + tid], s);
            s = fmaf(v.y, Wm1[(k + 1) * H_MOL + tid], s);
            s = fmaf(v.z, Wm1[(k + 2) * H_MOL + tid], s);
            s = fmaf(v.w, Wm1[(k + 3) * H_MOL + tid], s);
        }
        t[tid] = sspf(s);
    }
    __syncthreads();
    {
        const int m = tid;
        float s = bm2[m];
        for (int h = 0; h < H_MOL; h += 4) {
            const float4 v = *(const float4*)&t[h];
            s = fmaf(v.x, Wm2[(h + 0) * MOLB + m], s);
            s = fmaf(v.y, Wm2[(h + 1) * MOLB + m], s);
            s = fmaf(v.z, Wm2[(h + 2) * MOLB + m], s);
            s = fmaf(v.w, Wm2[(h + 3) * MOLB + m], s);
        }
        atomicAdd(&mol_fp[(conf / N_CONFS_PER) * MOLB + m], s * boltz[conf]);
    }
}

// ---------------- final readout MLP + sigmoid ----------------
__global__ __launch_bounds__(256) void k_final(
    const float* __restrict__ mol_fp,
    const float* __restrict__ Wr1, const float* __restrict__ br1,
    const float* __restrict__ Wr2, const float* __restrict__ br2,
    float* __restrict__ out)
{
    __shared__ float mf[MOLB];
    __shared__ float t2[D];
    __shared__ float red[4];
    const int mol = blockIdx.x, tid = threadIdx.x;
    mf[tid]       = mol_fp[mol * MOLB + tid];
    mf[tid + 256] = mol_fp[mol * MOLB + tid + 256];
    __syncthreads();
    {
        float s = br1[tid];
        for (int k = 0; k < MOLB; k += 4) {
            const float4 v = *(const float4*)&mf[k];
            s = fmaf(v.x, Wr1[(k + 0) * D + tid], s);
            s = fmaf(v.y, Wr1[(k + 1) * D + tid], s);
            s = fmaf(v.z, Wr1[(k + 2) * D + tid], s);
            s = fmaf(v.w, Wr1[(k + 3) * D + tid], s);
        }
        t2[tid] = sspf(s);
    }
    __syncthreads();
    float p = t2[tid] * Wr2[tid];
#pragma unroll
    for (int o = 32; o > 0; o >>= 1) p += __shfl_down(p, o);
    if ((tid & 63) == 0) red[tid >> 6] = p;
    __syncthreads();
    if (tid == 0) {
        float logit = red[0] + red[1] + red[2] + red[3] + br2[0];
        out[mol] = 1.f / (1.f + expf(-logit));
    }
}

extern "C" void kernel_launch(void* const* d_in, const int* in_sizes, int n_in,
                              void* d_out, int out_size, void* d_ws, size_t ws_size,
                              hipStream_t stream)
{
    const int*   z     = (const int*)d_in[0];
    const float* xyz   = (const float*)d_in[1];
    const int*   nbr   = (const int*)d_in[2];
    const float* boltz = (const float*)d_in[3];
    const float* emb   = (const float*)d_in[4];
    const float* We1   = (const float*)d_in[5];
    const float* be1   = (const float*)d_in[6];
    const float* We2   = (const float*)d_in[7];
    const float* be2   = (const float*)d_in[8];
    const float* Wn    = (const float*)d_in[9];
    const float* bn    = (const float*)d_in[10];
    const float* Wu1   = (const float*)d_in[11];
    const float* bu1   = (const float*)d_in[12];
    const float* Wu2   = (const float*)d_in[13];
    const float* bu2   = (const float*)d_in[14];
    const float* Wm1   = (const float*)d_in[15];
    const float* bm1   = (const float*)d_in[16];
    const float* Wm2   = (const float*)d_in[17];
    const float* bm2   = (const float*)d_in[18];
    const float* Wr1   = (const float*)d_in[19];
    const float* br1   = (const float*)d_in[20];
    const float* Wr2   = (const float*)d_in[21];
    const float* br2   = (const float*)d_in[22];

    char* ws = (char*)d_ws;
    unsigned* cursors        = (unsigned*)ws;                   // 2560 B
    float*    mol_fp         = (float*)(ws + 2560);             // 131072 B -> 133632
    unsigned* esort          = (unsigned*)(ws + 133632);        // 2621440 B -> 2755072
    float*    conf_fp        = (float*)(ws + 2755072);          // 655360 B -> 3410432
    __hip_bfloat16* WT       = (__hip_bfloat16*)(ws + 3410432); // 1572864 B -> 4983296
    __hip_bfloat16* WT2      = (__hip_bfloat16*)(ws + 4983296); // 65536 B -> 5048832
    __hip_bfloat16* We1T     = (__hip_bfloat16*)(ws + 5048832); // 8192 B -> 5057024

    hipMemsetAsync(cursors, 0, 2560 + 131072, stream);          // cursors + mol_fp
    k_prep<<<3072, 256, 0, stream>>>(Wn, Wu1, Wu2, WT);
    k_prep2<<<144, 256, 0, stream>>>(We2, We1, WT2, We1T);
    k_scatter<<<(N_EDGES + 255) / 256, 256, 0, stream>>>(nbr, cursors, esort);
    k_main<<<N_CONFS, TPB, 0, stream>>>(z, xyz, emb, be1, be2, bn,
                                        bu1, bu2, WT, WT2, We1T, cursors, esort, conf_fp);
    k_mol<<<N_CONFS, 512, 0, stream>>>(conf_fp, Wm1, bm1, Wm2, bm2, boltz, mol_fp);
    k_final<<<N_MOLS, 256, 0, stream>>>(mol_fp, Wr1, br1, Wr2, br2, (float*)d_out);
}

// Round 16
// 844.614 us; speedup vs baseline: 1.5471x; 1.0132x over previous
//
#include <hip/hip_runtime.h>
#include <hip/hip_bf16.h>

#define N_MOLS      64
#define N_CONFS_PER 10
#define A_ATOMS     40
#define N_CONFS     640
#define N_ATOMS     25600
#define N_EDGES     409600
#define D           256
#define NG          32
#define NLAYERS     4
#define MOLB        512
#define H_MOL       384
#define EDGE_CAP    1024
#define EB          32    // edge batch
#define NBMAX       32    // max batches (EDGE_CAP/EB)
#define SHBP        36    // sHb row stride (halfwords)
#define SEFP        260   // sEFs row stride (halfwords)
#define SBH         256   // bf16 tile row stride (halfwords), XOR-swizzled
#define TPB         512   // 8 waves

typedef __attribute__((ext_vector_type(8))) short bshort8;
typedef __attribute__((ext_vector_type(4))) float f32x4;

// swizzled halfword index into a [48][SBH] bf16 tile (conflict-free b128 A-frag reads)
#define SWZ(row, hw) (((row) << 8) + ((hw) ^ (((row) & 7) << 3)))

// fast ssp via HW v_exp_f32/v_log_f32 (~6 inst); bf16 downstream rounding swamps 1-2ulp err
__device__ __forceinline__ float sspf(float x) {
    return fmaxf(x, 0.f) + __logf(1.f + __expf(-fabsf(x))) - 0.69314718055994531f;
}
__device__ __forceinline__ float b2f(short s) {
    union { unsigned u; float f; } u;
    u.u = ((unsigned)(unsigned short)s) << 16;
    return u.f;
}
__device__ __forceinline__ short f2bf(float x) {
    return (short)(unsigned short)((__float_as_uint(x) + 0x8000u) >> 16);
}
__device__ __forceinline__ unsigned pkbf(float lo_e, float hi_e) {
    return __builtin_amdgcn_perm(__float_as_uint(hi_e) + 0x8000u,
                                 __float_as_uint(lo_e) + 0x8000u, 0x07060302u);
}

// ---------------- merged prep: WT | WT2+We1T | edge scatter (ranged grid) ----------------
#define PREP_WT_BLOCKS   3072
#define PREP_W2_BLOCKS   144
#define PREP_SC_BLOCKS   1600
__global__ __launch_bounds__(256) void k_prep_all(
    const float* __restrict__ Wn, const float* __restrict__ Wu1,
    const float* __restrict__ Wu2, const float* __restrict__ We2,
    const float* __restrict__ We1, const int* __restrict__ nbr,
    __hip_bfloat16* __restrict__ WT, __hip_bfloat16* __restrict__ WT2,
    __hip_bfloat16* __restrict__ We1T,
    unsigned* __restrict__ cursors, unsigned* __restrict__ esort)
{
    const int bid = blockIdx.x;
    if (bid < PREP_WT_BLOCKS) {
        int idx = bid * 256 + threadIdx.x;          // 3*4*256*256
        int k = idx & 255;
        int n = (idx >> 8) & 255;
        int l = (idx >> 16) & 3;
        int mat = idx >> 18;
        const float* src = (mat == 0) ? Wn : (mat == 1) ? Wu1 : Wu2;
        WT[idx] = __float2bfloat16(src[((size_t)l * 256 + k) * 256 + n]);
    } else if (bid < PREP_WT_BLOCKS + PREP_W2_BLOCKS) {
        int idx = (bid - PREP_WT_BLOCKS) * 256 + threadIdx.x;   // 32768 + 4096
        if (idx < 32768) {
            int k = idx & 31;
            int n = (idx >> 5) & 255;
            int l = idx >> 13;
            WT2[idx] = __float2bfloat16(We2[((size_t)l * 32 + k) * 256 + n]);
        } else {
            int j = idx - 32768;
            int m = j & 31;
            int t = (j >> 5) & 31;
            int l = j >> 10;
            We1T[j] = __float2bfloat16(We1[((size_t)l * 32 + m) * 32 + t]);
        }
    } else {
        int e = (bid - PREP_WT_BLOCKS - PREP_W2_BLOCKS) * 256 + threadIdx.x;
        if (e >= N_EDGES) return;
        int a0 = nbr[2 * e], a1 = nbr[2 * e + 1];
        int conf = a0 / A_ATOMS;
        int a0l = a0 - conf * A_ATOMS;
        int a1l = a1 - conf * A_ATOMS;
        unsigned r = atomicAdd(&cursors[conf], 1u);
        if (r < EDGE_CAP) esort[conf * EDGE_CAP + r] = (unsigned)((a0l << 6) | a1l);
    }
}

// dense MFMA from bf16 swizzled tile: wave -> 3 m-tiles x n-tiles {2wv, 2wv+1}
__device__ __forceinline__ void mfma_dense8b(const short* __restrict__ src,
                                             const __hip_bfloat16* __restrict__ WT,
                                             f32x4 acc[3][2], int lane, int wv) {
    const int r = lane & 15, g = lane >> 4;
#pragma unroll
    for (int mt = 0; mt < 3; ++mt)
#pragma unroll
        for (int j = 0; j < 2; ++j) acc[mt][j] = (f32x4){0.f, 0.f, 0.f, 0.f};
#pragma unroll 2
    for (int kt = 0; kt < 8; ++kt) {
        const int ko = kt * 32 + g * 8;
        bshort8 a0 = *(const bshort8*)&src[SWZ(0 * 16 + r, ko)];
        bshort8 a1 = *(const bshort8*)&src[SWZ(1 * 16 + r, ko)];
        bshort8 a2 = *(const bshort8*)&src[SWZ(2 * 16 + r, ko)];
#pragma unroll
        for (int j = 0; j < 2; ++j) {
            const int nt = wv * 2 + j;
            bshort8 b = *(const bshort8*)&WT[(nt * 16 + r) * 256 + ko];
            acc[0][j] = __builtin_amdgcn_mfma_f32_16x16x32_bf16(a0, b, acc[0][j], 0, 0, 0);
            acc[1][j] = __builtin_amdgcn_mfma_f32_16x16x32_bf16(a1, b, acc[1][j], 0, 0, 0);
            acc[2][j] = __builtin_amdgcn_mfma_f32_16x16x32_bf16(a2, b, acc[2][j], 0, 0, 0);
        }
    }
}

// writeback: MODE 0: dst16 = bf16(acc+bias) ; 1: dst16 = bf16(ssp(acc+bias))
template <int MODE>
__device__ __forceinline__ void mfma_wb8b(const f32x4 acc[3][2], short* __restrict__ dst16,
                                          const float* __restrict__ bias, int lane, int wv) {
    const int cc = lane & 15, g = lane >> 4;
    const int cr = g * 4;
#pragma unroll
    for (int j = 0; j < 2; ++j) {
        const int col = (wv * 2 + j) * 16 + cc;
        const float bv = bias[col];
#pragma unroll
        for (int mt = 0; mt < 3; ++mt) {
            if (mt == 2 && g >= 2) continue;   // rows 40..47 are padding
#pragma unroll
            for (int reg = 0; reg < 4; ++reg) {
                const int row = mt * 16 + cr + reg;
                float v = acc[mt][j][reg] + bv;
                if (MODE == 1) v = sspf(v);
                dst16[SWZ(row, col)] = f2bf(v);
            }
        }
    }
}

// ---------------- main per-conformer kernel (+ fused mol MLP): 512 threads, 2 blocks/CU ----------------
__global__ __launch_bounds__(TPB, 4) void k_main(
    const int* __restrict__ z, const float* __restrict__ xyz,
    const float* __restrict__ emb,
    const float* __restrict__ be1, const float* __restrict__ be2,
    const float* __restrict__ bn,
    const float* __restrict__ bu1, const float* __restrict__ bu2,
    const __hip_bfloat16* __restrict__ WT,
    const __hip_bfloat16* __restrict__ WT2,
    const __hip_bfloat16* __restrict__ We1T,
    const unsigned* __restrict__ cursors, const unsigned* __restrict__ esort,
    const float* __restrict__ Wm1, const float* __restrict__ bm1,
    const float* __restrict__ Wm2, const float* __restrict__ bm2,
    const float* __restrict__ boltz, float* __restrict__ mol_fp)
{
    __shared__ short sRb[48 * SBH];           // r bf16, swizzled (24.6KB)
    __shared__ short sBb[48 * SBH];           // rn -> agg -> t bf16, swizzled (24.6KB)
    __shared__ __align__(16) char uEFbuf[EB * SEFP * 2];  // 16.6KB: sEFs | setup | colsum+t1
    __shared__ __align__(16) char sHbBuf[2 * EB * SHBP * 2]; // 4.6KB: sHb | setup sEdge
    __shared__ float sDall[EDGE_CAP];         // scaled distances, zero-padded (4KB)
    __shared__ unsigned short sCsr[2 * EDGE_CAP];          // (src<<10)|edge (4KB)
    __shared__ unsigned short sWin[A_ATOMS * (NBMAX + 1)]; // per-(atom,batch) cursor (2.6KB)
    __shared__ int sPtr[A_ATOMS + 1];

    short* sEFs = (short*)uEFbuf;
    float* colsum = (float*)uEFbuf;               // 256 f32 (end-of-kernel alias)
    float* t1 = (float*)(uEFbuf + 1024);          // 384 f32 (fused mol hidden layer)
    float (*sXYZ)[3] = (float(*)[3])uEFbuf;       // setup alias
    int* sZ   = (int*)(uEFbuf + 480);             // setup alias
    int* sDeg = (int*)(uEFbuf + 640);             // setup alias
    short (*sHb)[EB * SHBP] = (short(*)[EB * SHBP])sHbBuf;
    unsigned* sEdge = (unsigned*)sHbBuf;          // setup alias (4KB <= 4.6KB)

    const int tid  = threadIdx.x;
    const int lane = tid & 63;
    const int wv   = tid >> 6;        // 0..7
    const int c4   = lane << 2;
    const int conf = blockIdx.x;
    const int fr = lane & 15, fg = lane >> 4, g8 = (lane >> 4) << 3;
    const int mtx = wv & 1;           // X2 m-tile (waves 0..3)
    const int ttx = (wv >> 1) & 1;    // X2 t-tile

    if (tid < A_ATOMS) {
        int ga = conf * A_ATOMS + tid;
        sZ[tid] = z[ga];
        sXYZ[tid][0] = xyz[ga * 3 + 0];
        sXYZ[tid][1] = xyz[ga * 3 + 1];
        sXYZ[tid][2] = xyz[ga * 3 + 2];
        sDeg[tid] = 0;
    }
    for (int i = tid; i < 8 * SBH; i += TPB) {   // zero bf16 pad rows 40..47
        sRb[40 * SBH + i] = 0;
        sBb[40 * SBH + i] = 0;
    }
    __syncthreads();
    float embsum = 0.f;
    {   // embedding init: bf16 r + f32 emb partial (rows q::2, col c)
        const int c = tid & 255, q = tid >> 8;
        for (int aa = q; aa < A_ATOMS; aa += 2) {
            float v = emb[sZ[aa] * D + c];
            embsum += v;
            sRb[SWZ(aa, c)] = f2bf(v);
        }
    }
    int cnt = (int)cursors[conf];
    if (cnt > EDGE_CAP) cnt = EDGE_CAP;
    const unsigned* eptr = esort + conf * EDGE_CAP;
    for (int i = tid; i < cnt; i += TPB) {
        unsigned pe = eptr[i];
        sEdge[i] = pe;
        int a0l = (pe >> 6) & 63, a1l = pe & 63;
        float dx = sXYZ[a0l][0] - sXYZ[a1l][0];
        float dy = sXYZ[a0l][1] - sXYZ[a1l][1];
        float dz = sXYZ[a0l][2] - sXYZ[a1l][2];
        sDall[i] = sqrtf(dx * dx + dy * dy + dz * dz) * (31.0f / 5.0f);
        atomicAdd(&sDeg[a0l], 1);
        atomicAdd(&sDeg[a1l], 1);
    }
    for (int i = cnt + tid; i < EDGE_CAP; i += TPB) sDall[i] = 0.f;
    __syncthreads();
    if (tid == 0) {
        int s = 0;
        for (int a = 0; a < A_ATOMS; ++a) { sPtr[a] = s; s += sDeg[a]; }
        sPtr[A_ATOMS] = s;
    }
    __syncthreads();
    const int NB = (cnt + EB - 1) / EB;
    // ordered CSR fill + per-batch windows (thread a owns its segment)
    if (tid < A_ATOMS) {
        const int ps = sPtr[tid];
        int pos = ps;
        for (int i = 0; i < cnt; ++i) {
            unsigned pe = sEdge[i];
            int a0l = (pe >> 6) & 63, a1l = pe & 63;
            if (a0l == tid) sCsr[pos++] = (unsigned short)((a1l << 10) | i);
            if (a1l == tid) sCsr[pos++] = (unsigned short)((a0l << 10) | i);
        }
        int p = ps;
        for (int b = 0; b <= NB; ++b) {
            const int lim = b * EB;
            while (p < pos && (int)(sCsr[p] & 1023) < lim) ++p;
            sWin[tid * (NBMAX + 1) + b] = (unsigned short)p;
        }
    }

    // f32 per-column delta accumulator (2 regs: only column sums are needed)
    float csum[2] = {0.f, 0.f};

    for (int l = 0; l < NLAYERS; ++l) {
        __syncthreads();
        // ---- M1: sBb = bf16(r @ Wn + bn)
        {
            f32x4 acc[3][2];
            mfma_dense8b(sRb, WT + ((size_t)(0 * 4 + l) << 16), acc, lane, wv);
            mfma_wb8b<0>(acc, sBb, bn + l * D, lane, wv);
        }
        __syncthreads();
        // ---- edge phase: balanced 2-barrier pipeline, batches of 32
        float4 agg[5];
#pragma unroll
        for (int k = 0; k < 5; ++k) agg[k] = make_float4(0.f, 0.f, 0.f, 0.f);
        {
            const bshort8 bf0 = *(const bshort8*)&WT2[(size_t)l * 8192 + ((2 * wv + 0) * 16 + fr) * 32 + g8];
            const bshort8 bf1 = *(const bshort8*)&WT2[(size_t)l * 8192 + ((2 * wv + 1) * 16 + fr) * 32 + g8];
            const float bb0 = be2[l * D + (2 * wv + 0) * 16 + fr];
            const float bb1 = be2[l * D + (2 * wv + 1) * 16 + fr];
            const bshort8 bfX = *(const bshort8*)&We1T[(size_t)l * 1024 + (ttx * 16 + fr) * 32 + g8];
            const float bbX = be1[l * NG + ttx * 16 + fr];

            // prologue: X2(0) -> sHb[0] (waves 0..3)
            if (wv < 4 && NB > 0) {
                const float dd = sDall[mtx * 16 + fr];
                union { bshort8 v; unsigned u[4]; } ua;
#pragma unroll
                for (int j = 0; j < 4; ++j) {
                    const float u0 = dd - (float)(g8 + 2 * j + 0);
                    const float u1 = dd - (float)(g8 + 2 * j + 1);
                    ua.u[j] = pkbf(__expf(-0.5f * u0 * u0), __expf(-0.5f * u1 * u1));
                }
                f32x4 c = (f32x4){0.f, 0.f, 0.f, 0.f};
                c = __builtin_amdgcn_mfma_f32_16x16x32_bf16(ua.v, bfX, c, 0, 0, 0);
#pragma unroll
                for (int reg = 0; reg < 4; ++reg) {
                    const int erow = mtx * 16 + fg * 4 + reg;
                    sHb[0][erow * SHBP + ttx * 16 + fr] = f2bf(sspf(c[reg] + bbX));
                }
            }
            __syncthreads();
            for (int b = 0; b < NB; ++b) {
                const int base = b * EB;
                // ---- phase1: P4(b) all waves; X2(b+1) waves 0..3
                {
                    const short* __restrict__ hb = sHb[b & 1];
#pragma unroll
                    for (int mt = 0; mt < 2; ++mt) {
                        union { bshort8 v; short4 s[2]; } af;
                        af.s[0] = *(const short4*)&hb[(mt * 16 + fr) * SHBP + g8];
                        af.s[1] = *(const short4*)&hb[(mt * 16 + fr) * SHBP + g8 + 4];
                        f32x4 c0 = (f32x4){0.f, 0.f, 0.f, 0.f};
                        c0 = __builtin_amdgcn_mfma_f32_16x16x32_bf16(af.v, bf0, c0, 0, 0, 0);
                        f32x4 c1 = (f32x4){0.f, 0.f, 0.f, 0.f};
                        c1 = __builtin_amdgcn_mfma_f32_16x16x32_bf16(af.v, bf1, c1, 0, 0, 0);
#pragma unroll
                        for (int reg = 0; reg < 4; ++reg) {
                            const int erow = mt * 16 + fg * 4 + reg;
                            sEFs[erow * SEFP + (2 * wv + 0) * 16 + fr] = f2bf(c0[reg] + bb0);
                            sEFs[erow * SEFP + (2 * wv + 1) * 16 + fr] = f2bf(c1[reg] + bb1);
                        }
                    }
                }
                if (wv < 4 && b + 1 < NB) {
                    short* __restrict__ hb = sHb[(b + 1) & 1];
                    const float dd = sDall[(b + 1) * EB + mtx * 16 + fr];
                    union { bshort8 v; unsigned u[4]; } ua;
#pragma unroll
                    for (int j = 0; j < 4; ++j) {
                        const float u0 = dd - (float)(g8 + 2 * j + 0);
                        const float u1 = dd - (float)(g8 + 2 * j + 1);
                        ua.u[j] = pkbf(__expf(-0.5f * u0 * u0), __expf(-0.5f * u1 * u1));
                    }
                    f32x4 c = (f32x4){0.f, 0.f, 0.f, 0.f};
                    c = __builtin_amdgcn_mfma_f32_16x16x32_bf16(ua.v, bfX, c, 0, 0, 0);
#pragma unroll
                    for (int reg = 0; reg < 4; ++reg) {
                        const int erow = mtx * 16 + fg * 4 + reg;
                        hb[erow * SHBP + ttx * 16 + fr] = f2bf(sspf(c[reg] + bbX));
                    }
                }
                __syncthreads();
                // ---- phase2: P5 counted gathers (wave owns rows 5wv..5wv+4)
#pragma unroll
                for (int k = 0; k < 5; ++k) {
                    const int row = wv * 5 + k;
                    const int st = (int)sWin[row * (NBMAX + 1) + b];
                    const int en = (int)sWin[row * (NBMAX + 1) + b + 1];
                    for (int i = st; i < en; ++i) {
                        const int ent = (int)sCsr[i];
                        const int e = ent & 1023, src = ent >> 10;
                        const short4 f4 = *(const short4*)&sEFs[(e - base) * SEFP + c4];
                        const short4 r4 = *(const short4*)&sBb[SWZ(src, c4)];
                        agg[k].x = fmaf(b2f(f4.x), b2f(r4.x), agg[k].x);
                        agg[k].y = fmaf(b2f(f4.y), b2f(r4.y), agg[k].y);
                        agg[k].z = fmaf(b2f(f4.z), b2f(r4.z), agg[k].z);
                        agg[k].w = fmaf(b2f(f4.w), b2f(r4.w), agg[k].w);
                    }
                }
                __syncthreads();
            }
        }
        // agg -> sBb (rn dead)
#pragma unroll
        for (int k = 0; k < 5; ++k) {
            uint2 p;
            p.x = pkbf(agg[k].x, agg[k].y);
            p.y = pkbf(agg[k].z, agg[k].w);
            *(uint2*)&sBb[SWZ(wv * 5 + k, c4)] = p;
        }
        __syncthreads();
        // ---- M2: sBb = bf16(ssp(agg @ Wu1 + bu1))  (in-place: sync between acc and wb)
        {
            f32x4 acc[3][2];
            mfma_dense8b(sBb, WT + ((size_t)(1 * 4 + l) << 16), acc, lane, wv);
            __syncthreads();
            mfma_wb8b<1>(acc, sBb, bu1 + l * D, lane, wv);
        }
        __syncthreads();
        // ---- M3: delta = t @ Wu2 + bu2; csum[j] += col-sum of delta (f32); r_bf16 += delta
        {
            f32x4 acc[3][2];
            mfma_dense8b(sBb, WT + ((size_t)(2 * 4 + l) << 16), acc, lane, wv);
            const int cc = lane & 15, g = lane >> 4, cr = g * 4;
#pragma unroll
            for (int j = 0; j < 2; ++j) {
                const int col = (wv * 2 + j) * 16 + cc;
                const float bv = bu2[l * D + col];
#pragma unroll
                for (int mt = 0; mt < 3; ++mt) {
                    if (mt == 2 && g >= 2) continue;
#pragma unroll
                    for (int reg = 0; reg < 4; ++reg) {
                        const int row = mt * 16 + cr + reg;
                        float v = acc[mt][j][reg] + bv;
                        csum[j] += v;
                        const int idx = SWZ(row, col);
                        sRb[idx] = f2bf(b2f(sRb[idx]) + v);
                    }
                }
            }
        }
    }
    // ---- conf_fp (in LDS) = sum over atoms of (emb + sum of deltas), all f32
    __syncthreads();
    if (tid < D) colsum[tid] = 0.f;
    __syncthreads();
    {
        const int cc = lane & 15;
#pragma unroll
        for (int j = 0; j < 2; ++j)
            atomicAdd(&colsum[(wv * 2 + j) * 16 + cc], csum[j]);
        atomicAdd(&colsum[tid & 255], embsum);
    }
    __syncthreads();
    // ---- fused mol MLP: t1 = ssp(conf_fp @ Wm1 + bm1); mol_fp += boltz*(t1 @ Wm2 + bm2)
    if (tid < H_MOL) {
        float s = bm1[tid];
        for (int k = 0; k < D; k += 4) {
            const float4 v = *(const float4*)&colsum[k];
            s = fmaf(v.x, Wm1[(k + 0) * H_MOL + tid], s);
            s = fmaf(v.y, Wm1[(k + 1) * H_MOL + tid], s);
            s = fmaf(v.z, Wm1[(k + 2) * H_MOL + tid], s);
            s = fmaf(v.w, Wm1[(k + 3) * H_MOL + tid], s);
        }
        t1[tid] = sspf(s);
    }
    __syncthreads();
    {
        float s = bm2[tid];
        for (int h = 0; h < H_MOL; h += 4) {
            const float4 v = *(const float4*)&t1[h];
            s = fmaf(v.x, Wm2[(h + 0) * MOLB + tid], s);
            s = fmaf(v.y, Wm2[(h + 1) * MOLB + tid], s);
            s = fmaf(v.z, Wm2[(h + 2) * MOLB + tid], s);
            s = fmaf(v.w, Wm2[(h + 3) * MOLB + tid], s);
        }
        atomicAdd(&mol_fp[(conf / N_CONFS_PER) * MOLB + tid], s * boltz[conf]);
    }
}

// ---------------- final readout MLP + sigmoid ----------------
__global__ __launch_bounds__(256) void k_final(
    const float* __restrict__ mol_fp,
    const float* __restrict__ Wr1, const float* __restrict__ br1,
    const float* __restrict__ Wr2, const float* __restrict__ br2,
    float* __restrict__ out)
{
    __shared__ float mf[MOLB];
    __shared__ float t2[D];
    __shared__ float red[4];
    const int mol = blockIdx.x, tid = threadIdx.x;
    mf[tid]       = mol_fp[mol * MOLB + tid];
    mf[tid + 256] = mol_fp[mol * MOLB + tid + 256];
    __syncthreads();
    {
        float s = br1[tid];
        for (int k = 0; k < MOLB; k += 4) {
            const float4 v = *(const float4*)&mf[k];
            s = fmaf(v.x, Wr1[(k + 0) * D + tid], s);
            s = fmaf(v.y, Wr1[(k + 1) * D + tid], s);
            s = fmaf(v.z, Wr1[(k + 2) * D + tid], s);
            s = fmaf(v.w, Wr1[(k + 3) * D + tid], s);
        }
        t2[tid] = sspf(s);
    }
    __syncthreads();
    float p = t2[tid] * Wr2[tid];
#pragma unroll
    for (int o = 32; o > 0; o >>= 1) p += __shfl_down(p, o);
    if ((tid & 63) == 0) red[tid >> 6] = p;
    __syncthreads();
    if (tid == 0) {
        float logit = red[0] + red[1] + red[2] + red[3] + br2[0];
        out[mol] = 1.f / (1.f + expf(-logit));
    }
}

extern "C" void kernel_launch(void* const* d_in, const int* in_sizes, int n_in,
                              void* d_out, int out_size, void* d_ws, size_t ws_size,
                              hipStream_t stream)
{
    const int*   z     = (const int*)d_in[0];
    const float* xyz   = (const float*)d_in[1];
    const int*   nbr   = (const int*)d_in[2];
    const float* boltz = (const float*)d_in[3];
    const float* emb   = (const float*)d_in[4];
    const float* We1   = (const float*)d_in[5];
    const float* be1   = (const float*)d_in[6];
    const float* We2   = (const float*)d_in[7];
    const float* be2   = (const float*)d_in[8];
    const float* Wn    = (const float*)d_in[9];
    const float* bn    = (const float*)d_in[10];
    const float* Wu1   = (const float*)d_in[11];
    const float* bu1   = (const float*)d_in[12];
    const float* Wu2   = (const float*)d_in[13];
    const float* bu2   = (const float*)d_in[14];
    const float* Wm1   = (const float*)d_in[15];
    const float* bm1   = (const float*)d_in[16];
    const float* Wm2   = (const float*)d_in[17];
    const float* bm2   = (const float*)d_in[18];
    const float* Wr1   = (const float*)d_in[19];
    const float* br1   = (const float*)d_in[20];
    const float* Wr2   = (const float*)d_in[21];
    const float* br2   = (const float*)d_in[22];

    char* ws = (char*)d_ws;
    unsigned* cursors        = (unsigned*)ws;                   // 2560 B
    float*    mol_fp         = (float*)(ws + 2560);             // 131072 B -> 133632
    unsigned* esort          = (unsigned*)(ws + 133632);        // 2621440 B -> 2755072
    __hip_bfloat16* WT       = (__hip_bfloat16*)(ws + 3410432); // 1572864 B -> 4983296
    __hip_bfloat16* WT2      = (__hip_bfloat16*)(ws + 4983296); // 65536 B -> 5048832
    __hip_bfloat16* We1T     = (__hip_bfloat16*)(ws + 5048832); // 8192 B -> 5057024

    hipMemsetAsync(cursors, 0, 2560 + 131072, stream);          // cursors + mol_fp
    k_prep_all<<<PREP_WT_BLOCKS + PREP_W2_BLOCKS + PREP_SC_BLOCKS, 256, 0, stream>>>(
        Wn, Wu1, Wu2, We2, We1, nbr, WT, WT2, We1T, cursors, esort);
    k_main<<<N_CONFS, TPB, 0, stream>>>(z, xyz, emb, be1, be2, bn,
                                        bu1, bu2, WT, WT2, We1T, cursors, esort,
                                        Wm1, bm1, Wm2, bm2, boltz, mol_fp);
    k_final<<<N_MOLS, 256, 0, stream>>>(mol_fp, Wr1, br1, Wr2, br2, (float*)d_out);
}